// Round 2
// baseline (1082.919 us; speedup 1.0000x reference)
//
#include <hip/hip_runtime.h>
#include <hip/hip_bf16.h>

typedef __attribute__((ext_vector_type(4))) float f32x4;
typedef __attribute__((ext_vector_type(8))) short short8;
typedef __attribute__((ext_vector_type(4))) short short4v;

namespace {

constexpr int Tt = 2048, Cc = 1024, Hh = 8, Dd = 128, FFNd = 4096;
constexpr int Bb = 2;
constexpr int Mrows = Bb * Tt;  // 4096
constexpr float kNEG = -1e30f;

static __device__ __forceinline__ float b2f(unsigned short u) {
  return __uint_as_float(((unsigned int)u) << 16);
}
static __device__ __forceinline__ unsigned short f2b(float f) {
  __hip_bfloat16 h = __float2bfloat16(f);
  unsigned short u;
  __builtin_memcpy(&u, &h, 2);
  return u;
}
// 2-way split: v = hi + lo + O(2^-18 v)
static __device__ __forceinline__ void split2(float v, unsigned short& h, unsigned short& l) {
  h = f2b(v);
  float r = v - b2f(h);  // exact
  l = f2b(r);
}
// 3-way split: v = hi + mid + lo + O(2^-27 v)
static __device__ __forceinline__ void split3(float v, unsigned short& h, unsigned short& m,
                                              unsigned short& l) {
  h = f2b(v);
  float r = v - b2f(h);  // exact
  m = f2b(r);
  float r2 = r - b2f(m);  // exact
  l = f2b(r2);
}
static __device__ __forceinline__ float wave_sum(float v) {
#pragma unroll
  for (int m = 1; m < 64; m <<= 1) v += __shfl_xor(v, m);
  return v;
}
static __device__ __forceinline__ float grp16_sum(float v) {
#pragma unroll
  for (int m = 1; m < 16; m <<= 1) v += __shfl_xor(v, m);
  return v;
}
static __device__ __forceinline__ float grp16_max(float v) {
#pragma unroll
  for (int m = 1; m < 16; m <<= 1) v = fmaxf(v, __shfl_xor(v, m));
  return v;
}

// ---------------- f32 -> bf16 cast (FFN weights only) ----------------
__global__ __launch_bounds__(256) void cast_kernel(const float* __restrict__ in,
                                                   unsigned short* __restrict__ out, int n) {
  int i = (blockIdx.x * 256 + threadIdx.x) * 4;
  if (i + 3 < n) {
    float4 v = *(const float4*)&in[i];
    short4v o;
    o.x = (short)f2b(v.x);
    o.y = (short)f2b(v.y);
    o.z = (short)f2b(v.z);
    o.w = (short)f2b(v.w);
    *(short4v*)&out[i] = o;
  }
}

// ---------------- LayerNorm (one wave per row), fp32 in -> fp32 out ----------------
__global__ __launch_bounds__(256) void ln_kernel(const float* __restrict__ x,
                                                 const float* __restrict__ g,
                                                 const float* __restrict__ bb,
                                                 float* __restrict__ out) {
  int row = blockIdx.x * 4 + (threadIdx.x >> 6);
  int lane = threadIdx.x & 63;
  const float* xr = x + (size_t)row * Cc;
  float v[16];
  float s = 0.f;
#pragma unroll
  for (int c = 0; c < 4; ++c) {
    float4 t = *(const float4*)&xr[c * 256 + lane * 4];
    v[c * 4 + 0] = t.x; v[c * 4 + 1] = t.y; v[c * 4 + 2] = t.z; v[c * 4 + 3] = t.w;
    s += t.x + t.y + t.z + t.w;
  }
  s = wave_sum(s);
  float mean = s * (1.f / Cc);
  float s2 = 0.f;
#pragma unroll
  for (int j = 0; j < 16; ++j) {
    float d = v[j] - mean;
    s2 += d * d;
  }
  s2 = wave_sum(s2);
  float rstd = 1.0f / sqrtf(s2 * (1.f / Cc) + 1e-5f);
#pragma unroll
  for (int c = 0; c < 4; ++c) {
    float4 o;
#pragma unroll
    for (int j = 0; j < 4; ++j) {
      int idx = c * 256 + lane * 4 + j;
      ((float*)&o)[j] = (v[c * 4 + j] - mean) * rstd * g[idx] + bb[idx];
    }
    *(float4*)&out[(size_t)row * Cc + c * 256 + lane * 4] = o;
  }
}

// ---------------- split-bf16 precise GEMM: C = A @ W^T, fp32 in/out ----------------
// NS=2: 3 MFMA terms (~2^-18); NS=3: 6 terms (~fp32-exact). 128x128 tile, BK=32.
template <int NS, int EPI>  // EPI: 0 = raw fp32, 1 = + resid
__global__ __launch_bounds__(256) void gemm_sp(const float* __restrict__ A,
                                               const float* __restrict__ W,
                                               float* __restrict__ outF,
                                               const float* __restrict__ resid, int Nn, int Kk) {
  __shared__ __align__(16) unsigned short As[NS][128 * 32];
  __shared__ __align__(16) unsigned short Bs[NS][128 * 32];
  int m0 = blockIdx.x * 128, n0 = blockIdx.y * 128;
  int tid = threadIdx.x, lane = tid & 63, wid = tid >> 6;
  int wr = (wid >> 1) * 64, wc = (wid & 1) * 64;
  int g = lane >> 4, r16 = lane & 15;
  f32x4 acc[4][4];
#pragma unroll
  for (int mi = 0; mi < 4; ++mi)
#pragma unroll
    for (int ni = 0; ni < 4; ++ni) acc[mi][ni] = (f32x4){0.f, 0.f, 0.f, 0.f};
  for (int k0 = 0; k0 < Kk; k0 += 32) {
    __syncthreads();
#pragma unroll
    for (int it = 0; it < 4; ++it) {
      int chunk = tid + it * 256;  // 0..1023
      int row = chunk >> 3, col4 = chunk & 7;
      int cc = col4 >> 1, half = col4 & 1;
      int off = row * 32 + ((cc ^ (row & 3)) * 8) + half * 4;
      float4 va = *(const float4*)&A[(size_t)(m0 + row) * Kk + k0 + col4 * 4];
      float4 vb = *(const float4*)&W[(size_t)(n0 + row) * Kk + k0 + col4 * 4];
      short4v sa[NS], sb[NS];
#pragma unroll
      for (int j = 0; j < 4; ++j) {
        unsigned short h, m, l;
        if constexpr (NS == 2) {
          split2(((float*)&va)[j], h, l);
          ((short*)&sa[0])[j] = (short)h; ((short*)&sa[1])[j] = (short)l;
          split2(((float*)&vb)[j], h, l);
          ((short*)&sb[0])[j] = (short)h; ((short*)&sb[1])[j] = (short)l;
        } else {
          split3(((float*)&va)[j], h, m, l);
          ((short*)&sa[0])[j] = (short)h; ((short*)&sa[1])[j] = (short)m; ((short*)&sa[2])[j] = (short)l;
          split3(((float*)&vb)[j], h, m, l);
          ((short*)&sb[0])[j] = (short)h; ((short*)&sb[1])[j] = (short)m; ((short*)&sb[2])[j] = (short)l;
        }
      }
#pragma unroll
      for (int s = 0; s < NS; ++s) {
        *(short4v*)&As[s][off] = sa[s];
        *(short4v*)&Bs[s][off] = sb[s];
      }
    }
    __syncthreads();
    short8 af[NS][4], bfv[NS][4];
#pragma unroll
    for (int mi = 0; mi < 4; ++mi) {
      int row = wr + mi * 16 + r16;
      int so = row * 32 + ((g ^ (row & 3)) * 8);
#pragma unroll
      for (int s = 0; s < NS; ++s) af[s][mi] = *(short8*)&As[s][so];
    }
#pragma unroll
    for (int ni = 0; ni < 4; ++ni) {
      int row = wc + ni * 16 + r16;
      int so = row * 32 + ((g ^ (row & 3)) * 8);
#pragma unroll
      for (int s = 0; s < NS; ++s) bfv[s][ni] = *(short8*)&Bs[s][so];
    }
#pragma unroll
    for (int mi = 0; mi < 4; ++mi)
#pragma unroll
      for (int ni = 0; ni < 4; ++ni) {
        f32x4 a = acc[mi][ni];
        if constexpr (NS == 3) {
          a = __builtin_amdgcn_mfma_f32_16x16x32_bf16(af[1][mi], bfv[1][ni], a, 0, 0, 0);
          a = __builtin_amdgcn_mfma_f32_16x16x32_bf16(af[0][mi], bfv[2][ni], a, 0, 0, 0);
          a = __builtin_amdgcn_mfma_f32_16x16x32_bf16(af[2][mi], bfv[0][ni], a, 0, 0, 0);
        }
        a = __builtin_amdgcn_mfma_f32_16x16x32_bf16(af[0][mi], bfv[1][ni], a, 0, 0, 0);
        a = __builtin_amdgcn_mfma_f32_16x16x32_bf16(af[1][mi], bfv[0][ni], a, 0, 0, 0);
        a = __builtin_amdgcn_mfma_f32_16x16x32_bf16(af[0][mi], bfv[0][ni], a, 0, 0, 0);
        acc[mi][ni] = a;
      }
  }
#pragma unroll
  for (int mi = 0; mi < 4; ++mi)
#pragma unroll
    for (int ni = 0; ni < 4; ++ni)
#pragma unroll
      for (int r = 0; r < 4; ++r) {
        int row = m0 + wr + mi * 16 + 4 * g + r;
        int col = n0 + wc + ni * 16 + r16;
        size_t o = (size_t)row * Nn + col;
        float v = acc[mi][ni][r];
        if constexpr (EPI == 0) outF[o] = v;
        else outF[o] = v + resid[o];
      }
}

// ---------------- bf16 MFMA GEMM for FFN ----------------
template <int EPI>  // 2: +bias, GELU -> bf16 ; 3: +bias, +resid -> fp32
__global__ __launch_bounds__(256) void gemm_bt(const unsigned short* __restrict__ A,
                                               const unsigned short* __restrict__ W,
                                               float* __restrict__ outF,
                                               unsigned short* __restrict__ outB,
                                               const float* __restrict__ bias,
                                               const float* __restrict__ resid, int Nn, int Kk) {
  __shared__ __align__(16) unsigned short As[128 * 32];
  __shared__ __align__(16) unsigned short Bs[128 * 32];
  int m0 = blockIdx.x * 128, n0 = blockIdx.y * 128;
  int tid = threadIdx.x, lane = tid & 63, wid = tid >> 6;
  int wr = (wid >> 1) * 64, wc = (wid & 1) * 64;
  int g = lane >> 4, r16 = lane & 15;
  f32x4 acc[4][4];
#pragma unroll
  for (int mi = 0; mi < 4; ++mi)
#pragma unroll
    for (int ni = 0; ni < 4; ++ni) acc[mi][ni] = (f32x4){0.f, 0.f, 0.f, 0.f};
  for (int k0 = 0; k0 < Kk; k0 += 32) {
    __syncthreads();
#pragma unroll
    for (int c = 0; c < 2; ++c) {
      int chunk = tid + c * 256;
      int row = chunk >> 2, cc = chunk & 3;
      int sw = cc ^ (row & 3);
      *(short8*)&As[row * 32 + sw * 8] = *(const short8*)&A[(size_t)(m0 + row) * Kk + k0 + cc * 8];
      *(short8*)&Bs[row * 32 + sw * 8] = *(const short8*)&W[(size_t)(n0 + row) * Kk + k0 + cc * 8];
    }
    __syncthreads();
    short8 af[4], bfr[4];
#pragma unroll
    for (int mi = 0; mi < 4; ++mi) {
      int row = wr + mi * 16 + r16;
      af[mi] = *(short8*)&As[row * 32 + ((g ^ (row & 3)) * 8)];
    }
#pragma unroll
    for (int ni = 0; ni < 4; ++ni) {
      int row = wc + ni * 16 + r16;
      bfr[ni] = *(short8*)&Bs[row * 32 + ((g ^ (row & 3)) * 8)];
    }
#pragma unroll
    for (int mi = 0; mi < 4; ++mi)
#pragma unroll
      for (int ni = 0; ni < 4; ++ni)
        acc[mi][ni] = __builtin_amdgcn_mfma_f32_16x16x32_bf16(af[mi], bfr[ni], acc[mi][ni], 0, 0, 0);
  }
#pragma unroll
  for (int mi = 0; mi < 4; ++mi)
#pragma unroll
    for (int ni = 0; ni < 4; ++ni)
#pragma unroll
      for (int r = 0; r < 4; ++r) {
        int row = m0 + wr + mi * 16 + 4 * g + r;
        int col = n0 + wc + ni * 16 + r16;
        size_t o = (size_t)row * Nn + col;
        float v = acc[mi][ni][r];
        if constexpr (EPI == 2) {
          v += bias[col];
          v = 0.5f * v * (1.f + erff(v * 0.70710678118654752f));
          outB[o] = f2b(v);
        } else {
          v += bias[col];
          outF[o] = v + resid[o];
        }
      }
}

// ---------------- RoPE tables (fp32, mirrors numpy ops) ----------------
__global__ __launch_bounds__(256) void rope_table(float* __restrict__ ct, float* __restrict__ st) {
  int idx = blockIdx.x * 256 + threadIdx.x;  // < T*64
  int t = idx >> 6, i = idx & 63;
  float e = (float)i * (1.f / 64.f);          // exact
  float p = powf(10000.0f, e);
  float inv = 1.0f / p;
  float ang = (float)t * inv;
  ct[idx] = cosf(ang);
  st[idx] = sinf(ang);
}

// ---------------- RoPE apply (fp32 in-place) + qp/kp trigram projections ----------------
__global__ __launch_bounds__(256) void rope_apply(float* __restrict__ qkv,
                                                  const float* __restrict__ ct,
                                                  const float* __restrict__ st,
                                                  float* __restrict__ qp, float* __restrict__ kp) {
  int w = blockIdx.x * 4 + (threadIdx.x >> 6);  // (b,h,t)
  int lane = threadIdx.x & 63;
  int b = w / (Hh * Tt);
  int rem = w % (Hh * Tt);
  int h = rem / Tt;
  int t = rem % Tt;
  size_t base = ((size_t)(b * Tt + t)) * 3 * Cc + h * Dd;
  float cv = ct[t * 64 + lane], sv = st[t * 64 + lane];
  float q_lo = qkv[base + lane], q_hi = qkv[base + lane + 64];
  float qn_lo = q_lo * cv - q_hi * sv;
  float qn_hi = q_hi * cv + q_lo * sv;
  qkv[base + lane] = qn_lo;
  qkv[base + lane + 64] = qn_hi;
  size_t kbase = base + Cc;
  float k_lo = qkv[kbase + lane], k_hi = qkv[kbase + lane + 64];
  float kn_lo = k_lo * cv - k_hi * sv;
  float kn_hi = k_hi * cv + k_lo * sv;
  qkv[kbase + lane] = kn_lo;
  qkv[kbase + lane + 64] = kn_hi;
  float d0 = (((h >> 0) & 1) ? 1.f : -1.f) * 0.57735026918962576f;
  float d1 = (((h >> 1) & 1) ? 1.f : -1.f) * 0.57735026918962576f;
  float d2 = (((h >> 2) & 1) ? 1.f : -1.f) * 0.57735026918962576f;
  float q0v = __shfl(qn_lo, 0), q1v = __shfl(qn_lo, 1), q2v = __shfl(qn_lo, 2);
  float k0v = __shfl(kn_lo, 0), k1v = __shfl(kn_lo, 1), k2v = __shfl(kn_lo, 2);
  if (lane == 0) {
    qp[(size_t)(b * Hh + h) * Tt + t] = q0v * d0 + q1v * d1 + q2v * d2;
    kp[(size_t)(b * Hh + h) * Tt + t] = k0v * d0 + k1v * d1 + k2v * d2;
  }
}

// ---------------- fused causal flash attention (std + geo), split-bf16, fp32 I/O -------
__global__ __launch_bounds__(256) void attn_fused(const float* __restrict__ qkv,
                                                  const float* __restrict__ qp,
                                                  const float* __restrict__ kp,
                                                  const float* __restrict__ head_scales,
                                                  float* __restrict__ out) {
  constexpr int KB = 32;
  int nq = Tt / 64;
  int bid = blockIdx.x;
  int bh = bid / nq, qblk = bid % nq;
  int b = bh / Hh, h = bh % Hh;
  int q0 = qblk * 64;
  int tid = threadIdx.x, lane = tid & 63, wid = tid >> 6;
  int wq0 = q0 + wid * 16;
  int g = lane >> 4, r16 = lane & 15;
  const float* Qb = qkv + (size_t)b * Tt * 3 * Cc + h * Dd;
  const float* Kb = Qb + Cc;
  const float* Vb = Qb + 2 * Cc;
  __shared__ __align__(16) unsigned short Ksh[KB * 128], Ksl[KB * 128];
  __shared__ __align__(16) unsigned short Vth[128 * 40], Vtl[128 * 40];
  __shared__ __align__(16) unsigned short PsAh[4][512], PsAl[4][512];
  __shared__ __align__(16) unsigned short PsGh[4][512], PsGl[4][512];

  short8 qh[4], qlo[4];
#pragma unroll
  for (int c = 0; c < 4; ++c) {
    const float* qptr = &Qb[(size_t)(wq0 + r16) * 3 * Cc + c * 32 + g * 8];
    float4 a = *(const float4*)qptr;
    float4 b4 = *(const float4*)(qptr + 4);
#pragma unroll
    for (int j = 0; j < 4; ++j) {
      unsigned short hh, ll;
      split2(((float*)&a)[j], hh, ll);
      ((short*)&qh[c])[j] = (short)hh; ((short*)&qlo[c])[j] = (short)ll;
      split2(((float*)&b4)[j], hh, ll);
      ((short*)&qh[c])[4 + j] = (short)hh; ((short*)&qlo[c])[4 + j] = (short)ll;
    }
  }

  float hs = head_scales[h];
  const float* qpb = qp + (size_t)bh * Tt;
  const float* kpb = kp + (size_t)bh * Tt;
  float qpv[4];
#pragma unroll
  for (int r = 0; r < 4; ++r) qpv[r] = qpb[wq0 + 4 * g + r];

  f32x4 accA[8], accG[8];
#pragma unroll
  for (int n = 0; n < 8; ++n) {
    accA[n] = (f32x4){0.f, 0.f, 0.f, 0.f};
    accG[n] = (f32x4){0.f, 0.f, 0.f, 0.f};
  }
  float m1[4], l1[4], m2[4], l2[4];
#pragma unroll
  for (int r = 0; r < 4; ++r) { m1[r] = kNEG; l1[r] = 0.f; m2[r] = kNEG; l2[r] = 0.f; }

  const float scale = 0.08838834764831845f;  // 1/sqrt(128)

  for (int s0 = 0; s0 < q0 + 64; s0 += KB) {
    __syncthreads();
#pragma unroll
    for (int it = 0; it < 4; ++it) {
      int chunk = tid + it * 256;   // 0..1023
      int row = chunk >> 5;         // key 0..31
      int col4 = chunk & 31;        // float4 within 128
      float4 kv = *(const float4*)&Kb[(size_t)(s0 + row) * 3 * Cc + col4 * 4];
      int cc = col4 >> 1, half = col4 & 1;
      int off = row * 128 + ((cc ^ (row & 7)) * 8) + half * 4;
      short4v h4, l4;
#pragma unroll
      for (int j = 0; j < 4; ++j) {
        unsigned short hh, ll;
        split2(((float*)&kv)[j], hh, ll);
        ((short*)&h4)[j] = (short)hh; ((short*)&l4)[j] = (short)ll;
      }
      *(short4v*)&Ksh[off] = h4;
      *(short4v*)&Ksl[off] = l4;
      float4 vv = *(const float4*)&Vb[(size_t)(s0 + row) * 3 * Cc + col4 * 4];
#pragma unroll
      for (int e = 0; e < 4; ++e) {
        unsigned short hh, ll;
        split2(((float*)&vv)[e], hh, ll);
        Vth[(col4 * 4 + e) * 40 + row] = hh;
        Vtl[(col4 * 4 + e) * 40 + row] = ll;
      }
    }
    __syncthreads();
    if (s0 <= wq0 + 15) {
      f32x4 sf[2];
      sf[0] = (f32x4){0.f, 0.f, 0.f, 0.f};
      sf[1] = (f32x4){0.f, 0.f, 0.f, 0.f};
#pragma unroll
      for (int st2 = 0; st2 < 2; ++st2) {
        int row = st2 * 16 + r16;
        int rsw = row & 7;
#pragma unroll
        for (int c = 0; c < 4; ++c) {
          int off = row * 128 + (((c * 4 + g) ^ rsw) * 8);
          short8 kh = *(short8*)&Ksh[off];
          short8 kl = *(short8*)&Ksl[off];
          sf[st2] = __builtin_amdgcn_mfma_f32_16x16x32_bf16(qlo[c], kh, sf[st2], 0, 0, 0);
          sf[st2] = __builtin_amdgcn_mfma_f32_16x16x32_bf16(qh[c], kl, sf[st2], 0, 0, 0);
          sf[st2] = __builtin_amdgcn_mfma_f32_16x16x32_bf16(qh[c], kh, sf[st2], 0, 0, 0);
        }
      }
      float kpv2[2];
      kpv2[0] = kpb[s0 + r16];
      kpv2[1] = kpb[s0 + 16 + r16];
      float pA[2][4], pG[2][4], scl1[4], scl2[4];
#pragma unroll
      for (int r = 0; r < 4; ++r) {
        int i = wq0 + 4 * g + r;
        bool ok0 = (s0 + r16) <= i;
        bool ok1 = (s0 + 16 + r16) <= i;
        float sv0 = ok0 ? sf[0][r] * scale : kNEG;
        float sv1 = ok1 ? sf[1][r] * scale : kNEG;
        float tm = grp16_max(fmaxf(sv0, sv1));
        float mn = fmaxf(m1[r], tm);
        float sc = expf(m1[r] - mn);
        float p0 = ok0 ? expf(sf[0][r] * scale - mn) : 0.f;
        float p1 = ok1 ? expf(sf[1][r] * scale - mn) : 0.f;
        l1[r] = l1[r] * sc + grp16_sum(p0 + p1);
        m1[r] = mn; scl1[r] = sc; pA[0][r] = p0; pA[1][r] = p1;
        float gv0 = qpv[r] * kpv2[0];
        float gv1 = qpv[r] * kpv2[1];
        float g0 = ok0 ? gv0 : kNEG;
        float g1 = ok1 ? gv1 : kNEG;
        float tg = grp16_max(fmaxf(g0, g1));
        float mg = fmaxf(m2[r], tg);
        float sg = expf(m2[r] - mg);
        float pg0 = ok0 ? expf(gv0 - mg) : 0.f;
        float pg1 = ok1 ? expf(gv1 - mg) : 0.f;
        l2[r] = l2[r] * sg + grp16_sum(pg0 + pg1);
        m2[r] = mg; scl2[r] = sg; pG[0][r] = pg0; pG[1][r] = pg1;
      }
#pragma unroll
      for (int n = 0; n < 8; ++n)
#pragma unroll
        for (int r = 0; r < 4; ++r) {
          accA[n][r] *= scl1[r];
          accG[n][r] *= scl2[r];
        }
#pragma unroll
      for (int st2 = 0; st2 < 2; ++st2)
#pragma unroll
        for (int r = 0; r < 4; ++r) {
          int rowp = 4 * g + r;
          int cbase = st2 * 2 + (r16 >> 3);
          int cs = cbase ^ (rowp & 3);
          int off = rowp * 32 + cs * 8 + (r16 & 7);
          unsigned short hh, ll;
          split2(pA[st2][r], hh, ll);
          PsAh[wid][off] = hh; PsAl[wid][off] = ll;
          split2(pG[st2][r], hh, ll);
          PsGh[wid][off] = hh; PsGl[wid][off] = ll;
        }
      int po = r16 * 32 + ((g ^ (r16 & 3)) * 8);
      short8 aph = *(short8*)&PsAh[wid][po];
      short8 apl = *(short8*)&PsAl[wid][po];
      short8 agh = *(short8*)&PsGh[wid][po];
      short8 agl = *(short8*)&PsGl[wid][po];
#pragma unroll
      for (int n = 0; n < 8; ++n) {
        int vo = (n * 16 + r16) * 40 + g * 8;
        short8 bvh = *(short8*)&Vth[vo];
        short8 bvl = *(short8*)&Vtl[vo];
        accA[n] = __builtin_amdgcn_mfma_f32_16x16x32_bf16(apl, bvh, accA[n], 0, 0, 0);
        accA[n] = __builtin_amdgcn_mfma_f32_16x16x32_bf16(aph, bvl, accA[n], 0, 0, 0);
        accA[n] = __builtin_amdgcn_mfma_f32_16x16x32_bf16(aph, bvh, accA[n], 0, 0, 0);
        accG[n] = __builtin_amdgcn_mfma_f32_16x16x32_bf16(agl, bvh, accG[n], 0, 0, 0);
        accG[n] = __builtin_amdgcn_mfma_f32_16x16x32_bf16(agh, bvl, accG[n], 0, 0, 0);
        accG[n] = __builtin_amdgcn_mfma_f32_16x16x32_bf16(agh, bvh, accG[n], 0, 0, 0);
      }
    }
  }
#pragma unroll
  for (int n = 0; n < 8; ++n)
#pragma unroll
    for (int r = 0; r < 4; ++r) {
      int i = wq0 + 4 * g + r;
      float av = accA[n][r] / l1[r];
      float gv = accG[n][r] / l2[r];
      out[(size_t)(b * Tt + i) * Cc + h * Dd + n * 16 + r16] = av + hs * (gv - av);
    }
}

// ---------------- hexagram VQ + FFN-LN prep (fp32, x1 updated in place) ------
__global__ __launch_bounds__(256) void hex_kernel(float* __restrict__ x1,
                                                  const float* __restrict__ hg,
                                                  const float* __restrict__ hb,
                                                  const float* __restrict__ to_qd,
                                                  const float* __restrict__ from_qd,
                                                  const float* __restrict__ hex_scale,
                                                  const float* __restrict__ fg,
                                                  const float* __restrict__ fb,
                                                  unsigned short* __restrict__ h_ffn) {
  int row = blockIdx.x * 4 + (threadIdx.x >> 6);
  int lane = threadIdx.x & 63;
  float* xr = x1 + (size_t)row * Cc;
  float v[16];
  float s = 0.f;
#pragma unroll
  for (int c = 0; c < 4; ++c) {
    float4 t = *(const float4*)&xr[c * 256 + lane * 4];
    v[c * 4 + 0] = t.x; v[c * 4 + 1] = t.y; v[c * 4 + 2] = t.z; v[c * 4 + 3] = t.w;
    s += t.x + t.y + t.z + t.w;
  }
  s = wave_sum(s);
  float mean = s * (1.f / Cc);
  float s2 = 0.f;
#pragma unroll
  for (int j = 0; j < 16; ++j) { float d = v[j] - mean; s2 += d * d; }
  s2 = wave_sum(s2);
  float rstd = 1.0f / sqrtf(s2 * (1.f / Cc) + 1e-5f);
  float zq[6] = {0.f, 0.f, 0.f, 0.f, 0.f, 0.f};
#pragma unroll
  for (int c = 0; c < 4; ++c)
#pragma unroll
    for (int j2 = 0; j2 < 4; ++j2) {
      int idx = c * 256 + lane * 4 + j2;
      float hv = (v[c * 4 + j2] - mean) * rstd * hg[idx] + hb[idx];
#pragma unroll
      for (int j = 0; j < 6; ++j) zq[j] += hv * to_qd[j * Cc + idx];
    }
#pragma unroll
  for (int j = 0; j < 6; ++j) zq[j] = wave_sum(zq[j]);
  float hsc = hex_scale[0];
  float hard[6];
#pragma unroll
  for (int j = 0; j < 6; ++j) hard[j] = (zq[j] >= 0.f) ? hsc : -hsc;
  float x2v[16];
  float t1 = 0.f;
#pragma unroll
  for (int c = 0; c < 4; ++c)
#pragma unroll
    for (int j2 = 0; j2 < 4; ++j2) {
      int idx = c * 256 + lane * 4 + j2;
      float a = 0.f;
#pragma unroll
      for (int j = 0; j < 6; ++j) a += hard[j] * from_qd[idx * 6 + j];
      float xv = v[c * 4 + j2] + a;
      x2v[c * 4 + j2] = xv;
      t1 += xv;
    }
  t1 = wave_sum(t1);
  float mean2 = t1 * (1.f / Cc);
  float t2 = 0.f;
#pragma unroll
  for (int j = 0; j < 16; ++j) { float d = x2v[j] - mean2; t2 += d * d; }
  t2 = wave_sum(t2);
  float rstd2 = 1.0f / sqrtf(t2 * (1.f / Cc) + 1e-5f);
#pragma unroll
  for (int c = 0; c < 4; ++c) {
    float4 t;
    t.x = x2v[c * 4 + 0]; t.y = x2v[c * 4 + 1]; t.z = x2v[c * 4 + 2]; t.w = x2v[c * 4 + 3];
    *(float4*)&xr[c * 256 + lane * 4] = t;
    short4v o;
#pragma unroll
    for (int j = 0; j < 4; ++j) {
      int idx = c * 256 + lane * 4 + j;
      ((short*)&o)[j] = (short)f2b((x2v[c * 4 + j] - mean2) * rstd2 * fg[idx] + fb[idx]);
    }
    *(short4v*)&h_ffn[(size_t)row * Cc + c * 256 + lane * 4] = o;
  }
}

}  // namespace

extern "C" void kernel_launch(void* const* d_in, const int* in_sizes, int n_in, void* d_out,
                              int out_size, void* d_ws, size_t ws_size, hipStream_t stream) {
  const float* x = (const float*)d_in[0];
  const float* ln_attn_g = (const float*)d_in[1];
  const float* ln_attn_b = (const float*)d_in[2];
  const float* qkv_w = (const float*)d_in[3];
  const float* out_w = (const float*)d_in[4];
  const float* head_scales = (const float*)d_in[5];
  const float* ln_hex_g = (const float*)d_in[6];
  const float* ln_hex_b = (const float*)d_in[7];
  const float* to_qd_w = (const float*)d_in[8];
  const float* from_qd_w = (const float*)d_in[9];
  const float* hex_scale = (const float*)d_in[10];
  const float* ln_ffn_g = (const float*)d_in[11];
  const float* ln_ffn_b = (const float*)d_in[12];
  const float* ffn_w1 = (const float*)d_in[13];
  const float* ffn_b1 = (const float*)d_in[14];
  const float* ffn_w2 = (const float*)d_in[15];
  const float* ffn_b2 = (const float*)d_in[16];

  char* ws = (char*)d_ws;
  size_t off = 0;
  auto alloc = [&](size_t bytes) -> char* {
    char* p = ws + off;
    off += (bytes + 255) & ~(size_t)255;
    return p;
  };
  float* qkv = (float*)alloc((size_t)Mrows * 3 * Cc * 4);        // 50.33 MB (gelu overlays)
  float* h = (float*)alloc((size_t)Mrows * Cc * 4);              // 16.78 MB (attn_out overlays)
  float* x1 = (float*)alloc((size_t)Mrows * Cc * 4);             // 16.78 MB
  unsigned short* h_ffn = (unsigned short*)alloc((size_t)Mrows * Cc * 2);  // 8.39 MB
  unsigned short* w1_b = (unsigned short*)alloc((size_t)FFNd * Cc * 2);    // 8.39 MB
  unsigned short* w2_b = (unsigned short*)alloc((size_t)Cc * FFNd * 2);    // 8.39 MB
  float* ct = (float*)alloc((size_t)Tt * 64 * 4);
  float* st = (float*)alloc((size_t)Tt * 64 * 4);
  float* qp = (float*)alloc((size_t)Bb * Hh * Tt * 4);
  float* kp = (float*)alloc((size_t)Bb * Hh * Tt * 4);
  float* attn_out = h;                    // h dead after QKV GEMM
  unsigned short* gelu = (unsigned short*)qkv;  // qkv dead after attention

  // FFN weight casts
  cast_kernel<<<(FFNd * Cc) / 1024, 256, 0, stream>>>(ffn_w1, w1_b, FFNd * Cc);
  cast_kernel<<<(Cc * FFNd) / 1024, 256, 0, stream>>>(ffn_w2, w2_b, Cc * FFNd);
  // LN(attn) fp32
  ln_kernel<<<Mrows / 4, 256, 0, stream>>>(x, ln_attn_g, ln_attn_b, h);
  // QKV GEMM (2-way split, fp32-out)
  gemm_sp<2, 0><<<dim3(Mrows / 128, (3 * Cc) / 128), 256, 0, stream>>>(h, qkv_w, qkv, nullptr,
                                                                       3 * Cc, Cc);
  // RoPE (fp32) + trigram projections
  rope_table<<<(Tt * 64) / 256, 256, 0, stream>>>(ct, st);
  rope_apply<<<(Bb * Hh * Tt) / 4, 256, 0, stream>>>(qkv, ct, st, qp, kp);
  // fused attention (std + geo), fp32 out
  attn_fused<<<Bb * Hh * (Tt / 64), 256, 0, stream>>>(qkv, qp, kp, head_scales, attn_out);
  // out-proj (3-way split) + residual -> x1
  gemm_sp<3, 1><<<dim3(Mrows / 128, Cc / 128), 256, 0, stream>>>(attn_out, out_w, x1, x, Cc, Cc);
  // hexagram VQ + FFN LN prep
  hex_kernel<<<Mrows / 4, 256, 0, stream>>>(x1, ln_hex_g, ln_hex_b, to_qd_w, from_qd_w, hex_scale,
                                            ln_ffn_g, ln_ffn_b, h_ffn);
  // FFN (bf16)
  gemm_bt<2><<<dim3(Mrows / 128, FFNd / 128), 256, 0, stream>>>(h_ffn, w1_b, nullptr, gelu,
                                                                ffn_b1, nullptr, FFNd, Cc);
  gemm_bt<3><<<dim3(Mrows / 128, Cc / 128), 256, 0, stream>>>(gelu, w2_b, (float*)d_out, nullptr,
                                                              ffn_b2, x1, Cc, FFNd);
}

// Round 3
// 662.958 us; speedup vs baseline: 1.6335x; 1.6335x over previous
//
#include <hip/hip_runtime.h>
#include <hip/hip_bf16.h>

typedef __attribute__((ext_vector_type(4))) float f32x4;
typedef __attribute__((ext_vector_type(8))) short short8;
typedef __attribute__((ext_vector_type(4))) short short4v;

namespace {

constexpr int Tt = 2048, Cc = 1024, Hh = 8, Dd = 128, FFNd = 4096;
constexpr int Bb = 2;
constexpr int Mrows = Bb * Tt;  // 4096
constexpr float kNEG = -1e30f;
constexpr float L2E = 1.4426950408889634f;

static __device__ __forceinline__ float b2f(unsigned short u) {
  return __uint_as_float(((unsigned int)u) << 16);
}
static __device__ __forceinline__ unsigned short f2b(float f) {
  __hip_bfloat16 h = __float2bfloat16(f);
  unsigned short u;
  __builtin_memcpy(&u, &h, 2);
  return u;
}
static __device__ __forceinline__ void split2(float v, unsigned short& h, unsigned short& l) {
  h = f2b(v);
  float r = v - b2f(h);  // exact
  l = f2b(r);
}
static __device__ __forceinline__ void split3(float v, unsigned short& h, unsigned short& m,
                                              unsigned short& l) {
  h = f2b(v);
  float r = v - b2f(h);
  m = f2b(r);
  float r2 = r - b2f(m);
  l = f2b(r2);
}
static __device__ __forceinline__ float wave_sum(float v) {
#pragma unroll
  for (int m = 1; m < 64; m <<= 1) v += __shfl_xor(v, m);
  return v;
}
static __device__ __forceinline__ float grp16_sum(float v) {
#pragma unroll
  for (int m = 1; m < 16; m <<= 1) v += __shfl_xor(v, m);
  return v;
}
static __device__ __forceinline__ float grp16_max(float v) {
#pragma unroll
  for (int m = 1; m < 16; m <<= 1) v = fmaxf(v, __shfl_xor(v, m));
  return v;
}

// ---------------- f32 -> bf16 cast (FFN weights) ----------------
__global__ __launch_bounds__(256) void cast_kernel(const float* __restrict__ in,
                                                   unsigned short* __restrict__ out, int n) {
  int i = (blockIdx.x * 256 + threadIdx.x) * 4;
  if (i + 3 < n) {
    float4 v = *(const float4*)&in[i];
    short4v o;
    o.x = (short)f2b(v.x);
    o.y = (short)f2b(v.y);
    o.z = (short)f2b(v.z);
    o.w = (short)f2b(v.w);
    *(short4v*)&out[i] = o;
  }
}

// ---------------- LayerNorm fp32 -> fp32 ----------------
__global__ __launch_bounds__(256) void ln_kernel(const float* __restrict__ x,
                                                 const float* __restrict__ g,
                                                 const float* __restrict__ bb,
                                                 float* __restrict__ out) {
  int row = blockIdx.x * 4 + (threadIdx.x >> 6);
  int lane = threadIdx.x & 63;
  const float* xr = x + (size_t)row * Cc;
  float v[16];
  float s = 0.f;
#pragma unroll
  for (int c = 0; c < 4; ++c) {
    float4 t = *(const float4*)&xr[c * 256 + lane * 4];
    v[c * 4 + 0] = t.x; v[c * 4 + 1] = t.y; v[c * 4 + 2] = t.z; v[c * 4 + 3] = t.w;
    s += t.x + t.y + t.z + t.w;
  }
  s = wave_sum(s);
  float mean = s * (1.f / Cc);
  float s2 = 0.f;
#pragma unroll
  for (int j = 0; j < 16; ++j) {
    float d = v[j] - mean;
    s2 += d * d;
  }
  s2 = wave_sum(s2);
  float rstd = 1.0f / sqrtf(s2 * (1.f / Cc) + 1e-5f);
#pragma unroll
  for (int c = 0; c < 4; ++c) {
    float4 o;
#pragma unroll
    for (int j = 0; j < 4; ++j) {
      int idx = c * 256 + lane * 4 + j;
      ((float*)&o)[j] = (v[c * 4 + j] - mean) * rstd * g[idx] + bb[idx];
    }
    *(float4*)&out[(size_t)row * Cc + c * 256 + lane * 4] = o;
  }
}

// ---------------- split-bf16 precise GEMM: C = A @ W^T, fp32 in ----------------
// EPI: 0 = fp32 raw, 1 = fp32 + resid, 2 = split2 bf16 pair out
template <int NS, int EPI>
__global__ __launch_bounds__(256) void gemm_sp(const float* __restrict__ A,
                                               const float* __restrict__ W,
                                               float* __restrict__ outF,
                                               unsigned short* __restrict__ outH,
                                               unsigned short* __restrict__ outL,
                                               const float* __restrict__ resid, int Nn, int Kk) {
  __shared__ __align__(16) unsigned short As[NS][128 * 32];
  __shared__ __align__(16) unsigned short Bs[NS][128 * 32];
  int m0 = blockIdx.x * 128, n0 = blockIdx.y * 128;
  int tid = threadIdx.x, lane = tid & 63, wid = tid >> 6;
  int wr = (wid >> 1) * 64, wc = (wid & 1) * 64;
  int g = lane >> 4, r16 = lane & 15;
  f32x4 acc[4][4];
#pragma unroll
  for (int mi = 0; mi < 4; ++mi)
#pragma unroll
    for (int ni = 0; ni < 4; ++ni) acc[mi][ni] = (f32x4){0.f, 0.f, 0.f, 0.f};
  for (int k0 = 0; k0 < Kk; k0 += 32) {
    __syncthreads();
#pragma unroll
    for (int it = 0; it < 4; ++it) {
      int chunk = tid + it * 256;  // 0..1023
      int row = chunk >> 3, col4 = chunk & 7;
      int cc = col4 >> 1, half = col4 & 1;
      int off = row * 32 + ((cc ^ (row & 3)) * 8) + half * 4;
      float4 va = *(const float4*)&A[(size_t)(m0 + row) * Kk + k0 + col4 * 4];
      float4 vb = *(const float4*)&W[(size_t)(n0 + row) * Kk + k0 + col4 * 4];
      short4v sa[NS], sb[NS];
#pragma unroll
      for (int j = 0; j < 4; ++j) {
        unsigned short h, m, l;
        if constexpr (NS == 2) {
          split2(((float*)&va)[j], h, l);
          ((short*)&sa[0])[j] = (short)h; ((short*)&sa[1])[j] = (short)l;
          split2(((float*)&vb)[j], h, l);
          ((short*)&sb[0])[j] = (short)h; ((short*)&sb[1])[j] = (short)l;
        } else {
          split3(((float*)&va)[j], h, m, l);
          ((short*)&sa[0])[j] = (short)h; ((short*)&sa[1])[j] = (short)m; ((short*)&sa[2])[j] = (short)l;
          split3(((float*)&vb)[j], h, m, l);
          ((short*)&sb[0])[j] = (short)h; ((short*)&sb[1])[j] = (short)m; ((short*)&sb[2])[j] = (short)l;
        }
      }
#pragma unroll
      for (int s = 0; s < NS; ++s) {
        *(short4v*)&As[s][off] = sa[s];
        *(short4v*)&Bs[s][off] = sb[s];
      }
    }
    __syncthreads();
    short8 af[NS][4], bfv[NS][4];
#pragma unroll
    for (int mi = 0; mi < 4; ++mi) {
      int row = wr + mi * 16 + r16;
      int so = row * 32 + ((g ^ (row & 3)) * 8);
#pragma unroll
      for (int s = 0; s < NS; ++s) af[s][mi] = *(short8*)&As[s][so];
    }
#pragma unroll
    for (int ni = 0; ni < 4; ++ni) {
      int row = wc + ni * 16 + r16;
      int so = row * 32 + ((g ^ (row & 3)) * 8);
#pragma unroll
      for (int s = 0; s < NS; ++s) bfv[s][ni] = *(short8*)&Bs[s][so];
    }
    __builtin_amdgcn_s_setprio(1);
#pragma unroll
    for (int mi = 0; mi < 4; ++mi)
#pragma unroll
      for (int ni = 0; ni < 4; ++ni) {
        f32x4 a = acc[mi][ni];
        if constexpr (NS == 3) {
          a = __builtin_amdgcn_mfma_f32_16x16x32_bf16(af[1][mi], bfv[1][ni], a, 0, 0, 0);
          a = __builtin_amdgcn_mfma_f32_16x16x32_bf16(af[0][mi], bfv[2][ni], a, 0, 0, 0);
          a = __builtin_amdgcn_mfma_f32_16x16x32_bf16(af[2][mi], bfv[0][ni], a, 0, 0, 0);
        }
        a = __builtin_amdgcn_mfma_f32_16x16x32_bf16(af[0][mi], bfv[1][ni], a, 0, 0, 0);
        a = __builtin_amdgcn_mfma_f32_16x16x32_bf16(af[1][mi], bfv[0][ni], a, 0, 0, 0);
        a = __builtin_amdgcn_mfma_f32_16x16x32_bf16(af[0][mi], bfv[0][ni], a, 0, 0, 0);
        acc[mi][ni] = a;
      }
    __builtin_amdgcn_s_setprio(0);
  }
#pragma unroll
  for (int mi = 0; mi < 4; ++mi)
#pragma unroll
    for (int ni = 0; ni < 4; ++ni)
#pragma unroll
      for (int r = 0; r < 4; ++r) {
        int row = m0 + wr + mi * 16 + 4 * g + r;
        int col = n0 + wc + ni * 16 + r16;
        size_t o = (size_t)row * Nn + col;
        float v = acc[mi][ni][r];
        if constexpr (EPI == 0) {
          outF[o] = v;
        } else if constexpr (EPI == 1) {
          outF[o] = v + resid[o];
        } else {
          unsigned short hh, ll;
          split2(v, hh, ll);
          outH[o] = hh;
          outL[o] = ll;
        }
      }
}

// ---------------- bf16 MFMA GEMM for FFN ----------------
template <int EPI>  // 2: +bias, GELU -> bf16 ; 3: +bias, +resid -> fp32
__global__ __launch_bounds__(256) void gemm_bt(const unsigned short* __restrict__ A,
                                               const unsigned short* __restrict__ W,
                                               float* __restrict__ outF,
                                               unsigned short* __restrict__ outB,
                                               const float* __restrict__ bias,
                                               const float* __restrict__ resid, int Nn, int Kk) {
  __shared__ __align__(16) unsigned short As[128 * 32];
  __shared__ __align__(16) unsigned short Bs[128 * 32];
  int m0 = blockIdx.x * 128, n0 = blockIdx.y * 128;
  int tid = threadIdx.x, lane = tid & 63, wid = tid >> 6;
  int wr = (wid >> 1) * 64, wc = (wid & 1) * 64;
  int g = lane >> 4, r16 = lane & 15;
  f32x4 acc[4][4];
#pragma unroll
  for (int mi = 0; mi < 4; ++mi)
#pragma unroll
    for (int ni = 0; ni < 4; ++ni) acc[mi][ni] = (f32x4){0.f, 0.f, 0.f, 0.f};
  for (int k0 = 0; k0 < Kk; k0 += 32) {
    __syncthreads();
#pragma unroll
    for (int c = 0; c < 2; ++c) {
      int chunk = tid + c * 256;
      int row = chunk >> 2, cc = chunk & 3;
      int sw = cc ^ (row & 3);
      *(short8*)&As[row * 32 + sw * 8] = *(const short8*)&A[(size_t)(m0 + row) * Kk + k0 + cc * 8];
      *(short8*)&Bs[row * 32 + sw * 8] = *(const short8*)&W[(size_t)(n0 + row) * Kk + k0 + cc * 8];
    }
    __syncthreads();
    short8 af[4], bfr[4];
#pragma unroll
    for (int mi = 0; mi < 4; ++mi) {
      int row = wr + mi * 16 + r16;
      af[mi] = *(short8*)&As[row * 32 + ((g ^ (row & 3)) * 8)];
    }
#pragma unroll
    for (int ni = 0; ni < 4; ++ni) {
      int row = wc + ni * 16 + r16;
      bfr[ni] = *(short8*)&Bs[row * 32 + ((g ^ (row & 3)) * 8)];
    }
    __builtin_amdgcn_s_setprio(1);
#pragma unroll
    for (int mi = 0; mi < 4; ++mi)
#pragma unroll
      for (int ni = 0; ni < 4; ++ni)
        acc[mi][ni] = __builtin_amdgcn_mfma_f32_16x16x32_bf16(af[mi], bfr[ni], acc[mi][ni], 0, 0, 0);
    __builtin_amdgcn_s_setprio(0);
  }
#pragma unroll
  for (int mi = 0; mi < 4; ++mi)
#pragma unroll
    for (int ni = 0; ni < 4; ++ni)
#pragma unroll
      for (int r = 0; r < 4; ++r) {
        int row = m0 + wr + mi * 16 + 4 * g + r;
        int col = n0 + wc + ni * 16 + r16;
        size_t o = (size_t)row * Nn + col;
        float v = acc[mi][ni][r];
        if constexpr (EPI == 2) {
          v += bias[col];
          v = 0.5f * v * (1.f + erff(v * 0.70710678118654752f));
          outB[o] = f2b(v);
        } else {
          v += bias[col];
          outF[o] = v + resid[o];
        }
      }
}

// ---------------- RoPE tables ----------------
__global__ __launch_bounds__(256) void rope_table(float* __restrict__ ct, float* __restrict__ st) {
  int idx = blockIdx.x * 256 + threadIdx.x;  // < T*64
  int t = idx >> 6, i = idx & 63;
  float e = (float)i * (1.f / 64.f);
  float p = powf(10000.0f, e);
  float inv = 1.0f / p;
  float ang = (float)t * inv;
  ct[idx] = cosf(ang);
  st[idx] = sinf(ang);
}

// ---------------- RoPE apply on split buffers; K -> swizzled global; qp/kp ----------------
__global__ __launch_bounds__(256) void rope_apply(unsigned short* __restrict__ qkvh,
                                                  unsigned short* __restrict__ qkvl,
                                                  unsigned short* __restrict__ khsw,
                                                  unsigned short* __restrict__ klsw,
                                                  const float* __restrict__ ct,
                                                  const float* __restrict__ st,
                                                  float* __restrict__ qp, float* __restrict__ kp) {
  int w = blockIdx.x * 4 + (threadIdx.x >> 6);  // (b,h,t)
  int lane = threadIdx.x & 63;
  int b = w / (Hh * Tt);
  int rem = w % (Hh * Tt);
  int h = rem / Tt;
  int t = rem % Tt;
  size_t base = ((size_t)(b * Tt + t)) * 3 * Cc + h * Dd;
  float cv = ct[t * 64 + lane], sv = st[t * 64 + lane];
  // Q
  float q_lo = b2f(qkvh[base + lane]) + b2f(qkvl[base + lane]);
  float q_hi = b2f(qkvh[base + lane + 64]) + b2f(qkvl[base + lane + 64]);
  float qn_lo = q_lo * cv - q_hi * sv;
  float qn_hi = q_hi * cv + q_lo * sv;
  unsigned short hh, ll;
  split2(qn_lo, hh, ll);
  qkvh[base + lane] = hh; qkvl[base + lane] = ll;
  split2(qn_hi, hh, ll);
  qkvh[base + lane + 64] = hh; qkvl[base + lane + 64] = ll;
  // K -> swizzled dedicated buffer
  size_t kbase = base + Cc;
  float k_lo = b2f(qkvh[kbase + lane]) + b2f(qkvl[kbase + lane]);
  float k_hi = b2f(qkvh[kbase + lane + 64]) + b2f(qkvl[kbase + lane + 64]);
  float kn_lo = k_lo * cv - k_hi * sv;
  float kn_hi = k_hi * cv + k_lo * sv;
  size_t krow = ((size_t)(b * Hh + h) * Tt + t) * 128;
  int tsw = t & 7;
  int d0 = lane, d1 = lane + 64;
  int c0 = (((d0 >> 3) ^ tsw) << 3) | (d0 & 7);
  int c1 = (((d1 >> 3) ^ tsw) << 3) | (d1 & 7);
  split2(kn_lo, hh, ll);
  khsw[krow + c0] = hh; klsw[krow + c0] = ll;
  split2(kn_hi, hh, ll);
  khsw[krow + c1] = hh; klsw[krow + c1] = ll;
  // trigram projections (fp32)
  float t0 = (((h >> 0) & 1) ? 1.f : -1.f) * 0.57735026918962576f;
  float t1 = (((h >> 1) & 1) ? 1.f : -1.f) * 0.57735026918962576f;
  float t2 = (((h >> 2) & 1) ? 1.f : -1.f) * 0.57735026918962576f;
  float q0v = __shfl(qn_lo, 0), q1v = __shfl(qn_lo, 1), q2v = __shfl(qn_lo, 2);
  float k0v = __shfl(kn_lo, 0), k1v = __shfl(kn_lo, 1), k2v = __shfl(kn_lo, 2);
  if (lane == 0) {
    qp[(size_t)(b * Hh + h) * Tt + t] = q0v * t0 + q1v * t1 + q2v * t2;
    kp[(size_t)(b * Hh + h) * Tt + t] = k0v * t0 + k1v * t1 + k2v * t2;
  }
}

// ---------------- V transpose: qkv split V-section -> vt[bh][d][t] ----------------
__global__ __launch_bounds__(256) void vtrans(const unsigned short* __restrict__ qkvh,
                                              const unsigned short* __restrict__ qkvl,
                                              unsigned short* __restrict__ vth,
                                              unsigned short* __restrict__ vtl) {
  __shared__ unsigned short Lh[64 * 68], Ll[64 * 68];
  int bidx = blockIdx.x;  // bh*64 + tt*2 + dd
  int dd = bidx & 1;
  int tt = (bidx >> 1) & 31;
  int bh = bidx >> 6;
  int b = bh >> 3, h = bh & 7;
  int tid = threadIdx.x;
#pragma unroll
  for (int it = 0; it < 2; ++it) {
    int chunk = tid + it * 256;  // 0..511
    int tr = chunk >> 3, c8 = chunk & 7;
    size_t src = ((size_t)(b * Tt + tt * 64 + tr)) * 3 * Cc + 2 * Cc + h * Dd + dd * 64 + c8 * 8;
    short8 vh = *(const short8*)&qkvh[src];
    short8 vl = *(const short8*)&qkvl[src];
    *(short4v*)&Lh[tr * 68 + c8 * 8] = *(short4v*)&vh;
    *(short4v*)&Lh[tr * 68 + c8 * 8 + 4] = *((short4v*)&vh + 1);
    *(short4v*)&Ll[tr * 68 + c8 * 8] = *(short4v*)&vl;
    *(short4v*)&Ll[tr * 68 + c8 * 8 + 4] = *((short4v*)&vl + 1);
  }
  __syncthreads();
#pragma unroll
  for (int it = 0; it < 2; ++it) {
    int chunk = tid + it * 256;
    int dr = chunk >> 3, t8 = chunk & 7;
    short8 oh, ol;
#pragma unroll
    for (int e = 0; e < 8; ++e) {
      oh[e] = (short)Lh[(t8 * 8 + e) * 68 + dr];
      ol[e] = (short)Ll[(t8 * 8 + e) * 68 + dr];
    }
    size_t dst = ((size_t)(bh * Dd + dd * 64 + dr)) * Tt + tt * 64 + t8 * 8;
    *(short8*)&vth[dst] = oh;
    *(short8*)&vtl[dst] = ol;
  }
}

// ---------------- fused causal flash attention (std + geo), pre-split inputs ----------
__global__ __launch_bounds__(256) void attn_fused(const unsigned short* __restrict__ qkvh,
                                                  const unsigned short* __restrict__ qkvl,
                                                  const unsigned short* __restrict__ khsw,
                                                  const unsigned short* __restrict__ klsw,
                                                  const unsigned short* __restrict__ vth,
                                                  const unsigned short* __restrict__ vtl,
                                                  const float* __restrict__ qp,
                                                  const float* __restrict__ kp,
                                                  const float* __restrict__ head_scales,
                                                  float* __restrict__ out) {
  int i = blockIdx.x;
  int bh = i & 15;
  int j = i >> 4;  // 0..31
  int qblk = (j < 16) ? (31 - j) : (j - 16);  // big blocks first; bid/bid+256 complementary
  int b = bh >> 3, h = bh & 7;
  int q0 = qblk * 64;
  int tid = threadIdx.x, lane = tid & 63, wid = tid >> 6;
  int wq0 = q0 + wid * 16;
  int g = lane >> 4, r16 = lane & 15;
  __shared__ __align__(16) unsigned short Ksh[32 * 128], Ksl[32 * 128];
  __shared__ __align__(16) unsigned short Vsh[128 * 40], Vsl[128 * 40];
  __shared__ __align__(16) unsigned short PsAh[4][512], PsAl[4][512];
  __shared__ __align__(16) unsigned short PsGh[4][512], PsGl[4][512];

  // Q fragments (pre-split, roped in place)
  short8 qh[4], ql[4];
#pragma unroll
  for (int c = 0; c < 4; ++c) {
    size_t qoff = (size_t)(b * Tt + wq0 + r16) * 3 * Cc + h * Dd + c * 32 + g * 8;
    qh[c] = *(const short8*)&qkvh[qoff];
    ql[c] = *(const short8*)&qkvl[qoff];
  }

  float hs = head_scales[h];
  const float* qpb = qp + (size_t)bh * Tt;
  const float* kpb = kp + (size_t)bh * Tt;
  float qpv[4];
#pragma unroll
  for (int r = 0; r < 4; ++r) qpv[r] = qpb[wq0 + 4 * g + r] * L2E;

  f32x4 accA[8], accG[8];
#pragma unroll
  for (int n = 0; n < 8; ++n) {
    accA[n] = (f32x4){0.f, 0.f, 0.f, 0.f};
    accG[n] = (f32x4){0.f, 0.f, 0.f, 0.f};
  }
  float m1[4], l1[4], m2[4], l2[4];
#pragma unroll
  for (int r = 0; r < 4; ++r) { m1[r] = kNEG; l1[r] = 0.f; m2[r] = kNEG; l2[r] = 0.f; }

  const float scale2 = 0.08838834764831845f * L2E;  // (1/sqrt(128))*log2e

  const unsigned short* Khb = khsw + (size_t)bh * Tt * 128;
  const unsigned short* Klb = klsw + (size_t)bh * Tt * 128;
  const unsigned short* Vhb = vth + (size_t)bh * Dd * Tt;
  const unsigned short* Vlb = vtl + (size_t)bh * Dd * Tt;

  for (int s0 = 0; s0 < q0 + 64; s0 += 32) {
    __syncthreads();
    // stage K (already swizzled in global) and Vt (pad 40)
#pragma unroll
    for (int it = 0; it < 2; ++it) {
      int chunk = tid + it * 256;  // 0..511
      int row = chunk >> 4, c8 = chunk & 15;
      size_t src = (size_t)(s0 + row) * 128 + c8 * 8;
      *(short8*)&Ksh[row * 128 + c8 * 8] = *(const short8*)&Khb[src];
      *(short8*)&Ksl[row * 128 + c8 * 8] = *(const short8*)&Klb[src];
    }
#pragma unroll
    for (int it = 0; it < 2; ++it) {
      int chunk = tid + it * 256;  // 0..511
      int d = chunk >> 2, k8 = chunk & 3;
      size_t src = (size_t)d * Tt + s0 + k8 * 8;
      *(short8*)&Vsh[d * 40 + k8 * 8] = *(const short8*)&Vhb[src];
      *(short8*)&Vsl[d * 40 + k8 * 8] = *(const short8*)&Vlb[src];
    }
    __syncthreads();
    if (s0 <= wq0 + 15) {
      f32x4 sf[2];
      sf[0] = (f32x4){0.f, 0.f, 0.f, 0.f};
      sf[1] = (f32x4){0.f, 0.f, 0.f, 0.f};
      __builtin_amdgcn_s_setprio(1);
#pragma unroll
      for (int st2 = 0; st2 < 2; ++st2) {
        int row = st2 * 16 + r16;
        int rsw = row & 7;
#pragma unroll
        for (int c = 0; c < 4; ++c) {
          int off = row * 128 + (((c * 4 + g) ^ rsw) * 8);
          short8 kh = *(short8*)&Ksh[off];
          short8 kl = *(short8*)&Ksl[off];
          sf[st2] = __builtin_amdgcn_mfma_f32_16x16x32_bf16(ql[c], kh, sf[st2], 0, 0, 0);
          sf[st2] = __builtin_amdgcn_mfma_f32_16x16x32_bf16(qh[c], kl, sf[st2], 0, 0, 0);
          sf[st2] = __builtin_amdgcn_mfma_f32_16x16x32_bf16(qh[c], kh, sf[st2], 0, 0, 0);
        }
      }
      __builtin_amdgcn_s_setprio(0);
      float kpv2[2];
      kpv2[0] = kpb[s0 + r16];
      kpv2[1] = kpb[s0 + 16 + r16];
      float pA[2][4], pG[2][4], scl1[4], scl2[4];
#pragma unroll
      for (int r = 0; r < 4; ++r) {
        int qi = wq0 + 4 * g + r;
        bool ok0 = (s0 + r16) <= qi;
        bool ok1 = (s0 + 16 + r16) <= qi;
        // standard path (log2 domain)
        float sv0 = ok0 ? sf[0][r] * scale2 : kNEG;
        float sv1 = ok1 ? sf[1][r] * scale2 : kNEG;
        float tm = grp16_max(fmaxf(sv0, sv1));
        float mn = fmaxf(m1[r], tm);
        float sc = exp2f(m1[r] - mn);
        float p0 = ok0 ? exp2f(sv0 - mn) : 0.f;
        float p1 = ok1 ? exp2f(sv1 - mn) : 0.f;
        l1[r] = l1[r] * sc + grp16_sum(p0 + p1);
        m1[r] = mn; scl1[r] = sc; pA[0][r] = p0; pA[1][r] = p1;
        // geo path (log2 domain; qpv pre-multiplied by log2e)
        float gv0 = qpv[r] * kpv2[0];
        float gv1 = qpv[r] * kpv2[1];
        float g0 = ok0 ? gv0 : kNEG;
        float g1 = ok1 ? gv1 : kNEG;
        float tg = grp16_max(fmaxf(g0, g1));
        float mg = fmaxf(m2[r], tg);
        float sg = exp2f(m2[r] - mg);
        float pg0 = ok0 ? exp2f(g0 - mg) : 0.f;
        float pg1 = ok1 ? exp2f(g1 - mg) : 0.f;
        l2[r] = l2[r] * sg + grp16_sum(pg0 + pg1);
        m2[r] = mg; scl2[r] = sg; pG[0][r] = pg0; pG[1][r] = pg1;
      }
#pragma unroll
      for (int n = 0; n < 8; ++n)
#pragma unroll
        for (int r = 0; r < 4; ++r) {
          accA[n][r] *= scl1[r];
          accG[n][r] *= scl2[r];
        }
      // P: D-layout -> LDS (split2) -> A-layout
#pragma unroll
      for (int st2 = 0; st2 < 2; ++st2)
#pragma unroll
        for (int r = 0; r < 4; ++r) {
          int rowp = 4 * g + r;
          int cbase = st2 * 2 + (r16 >> 3);
          int cs = cbase ^ (rowp & 3);
          int off = rowp * 32 + cs * 8 + (r16 & 7);
          unsigned short hh, ll;
          split2(pA[st2][r], hh, ll);
          PsAh[wid][off] = hh; PsAl[wid][off] = ll;
          split2(pG[st2][r], hh, ll);
          PsGh[wid][off] = hh; PsGl[wid][off] = ll;
        }
      int po = r16 * 32 + ((g ^ (r16 & 3)) * 8);
      short8 aph = *(short8*)&PsAh[wid][po];
      short8 apl = *(short8*)&PsAl[wid][po];
      short8 agh = *(short8*)&PsGh[wid][po];
      short8 agl = *(short8*)&PsGl[wid][po];
      __builtin_amdgcn_s_setprio(1);
#pragma unroll
      for (int n = 0; n < 8; ++n) {
        int vo = (n * 16 + r16) * 40 + g * 8;
        short8 bvh = *(short8*)&Vsh[vo];
        short8 bvl = *(short8*)&Vsl[vo];
        accA[n] = __builtin_amdgcn_mfma_f32_16x16x32_bf16(apl, bvh, accA[n], 0, 0, 0);
        accA[n] = __builtin_amdgcn_mfma_f32_16x16x32_bf16(aph, bvl, accA[n], 0, 0, 0);
        accA[n] = __builtin_amdgcn_mfma_f32_16x16x32_bf16(aph, bvh, accA[n], 0, 0, 0);
        accG[n] = __builtin_amdgcn_mfma_f32_16x16x32_bf16(agl, bvh, accG[n], 0, 0, 0);
        accG[n] = __builtin_amdgcn_mfma_f32_16x16x32_bf16(agh, bvl, accG[n], 0, 0, 0);
        accG[n] = __builtin_amdgcn_mfma_f32_16x16x32_bf16(agh, bvh, accG[n], 0, 0, 0);
      }
      __builtin_amdgcn_s_setprio(0);
    }
  }
#pragma unroll
  for (int n = 0; n < 8; ++n)
#pragma unroll
    for (int r = 0; r < 4; ++r) {
      int qi = wq0 + 4 * g + r;
      float av = accA[n][r] / l1[r];
      float gv = accG[n][r] / l2[r];
      out[(size_t)(b * Tt + qi) * Cc + h * Dd + n * 16 + r16] = av + hs * (gv - av);
    }
}

// ---------------- hexagram VQ + FFN-LN prep ----------------
__global__ __launch_bounds__(256) void hex_kernel(float* __restrict__ x1,
                                                  const float* __restrict__ hg,
                                                  const float* __restrict__ hb,
                                                  const float* __restrict__ to_qd,
                                                  const float* __restrict__ from_qd,
                                                  const float* __restrict__ hex_scale,
                                                  const float* __restrict__ fg,
                                                  const float* __restrict__ fb,
                                                  unsigned short* __restrict__ h_ffn) {
  int row = blockIdx.x * 4 + (threadIdx.x >> 6);
  int lane = threadIdx.x & 63;
  float* xr = x1 + (size_t)row * Cc;
  float v[16];
  float s = 0.f;
#pragma unroll
  for (int c = 0; c < 4; ++c) {
    float4 t = *(const float4*)&xr[c * 256 + lane * 4];
    v[c * 4 + 0] = t.x; v[c * 4 + 1] = t.y; v[c * 4 + 2] = t.z; v[c * 4 + 3] = t.w;
    s += t.x + t.y + t.z + t.w;
  }
  s = wave_sum(s);
  float mean = s * (1.f / Cc);
  float s2 = 0.f;
#pragma unroll
  for (int j = 0; j < 16; ++j) { float d = v[j] - mean; s2 += d * d; }
  s2 = wave_sum(s2);
  float rstd = 1.0f / sqrtf(s2 * (1.f / Cc) + 1e-5f);
  float zq[6] = {0.f, 0.f, 0.f, 0.f, 0.f, 0.f};
#pragma unroll
  for (int c = 0; c < 4; ++c)
#pragma unroll
    for (int j2 = 0; j2 < 4; ++j2) {
      int idx = c * 256 + lane * 4 + j2;
      float hv = (v[c * 4 + j2] - mean) * rstd * hg[idx] + hb[idx];
#pragma unroll
      for (int j = 0; j < 6; ++j) zq[j] += hv * to_qd[j * Cc + idx];
    }
#pragma unroll
  for (int j = 0; j < 6; ++j) zq[j] = wave_sum(zq[j]);
  float hsc = hex_scale[0];
  float hard[6];
#pragma unroll
  for (int j = 0; j < 6; ++j) hard[j] = (zq[j] >= 0.f) ? hsc : -hsc;
  float x2v[16];
  float t1 = 0.f;
#pragma unroll
  for (int c = 0; c < 4; ++c)
#pragma unroll
    for (int j2 = 0; j2 < 4; ++j2) {
      int idx = c * 256 + lane * 4 + j2;
      float a = 0.f;
#pragma unroll
      for (int j = 0; j < 6; ++j) a += hard[j] * from_qd[idx * 6 + j];
      float xv = v[c * 4 + j2] + a;
      x2v[c * 4 + j2] = xv;
      t1 += xv;
    }
  t1 = wave_sum(t1);
  float mean2 = t1 * (1.f / Cc);
  float t2 = 0.f;
#pragma unroll
  for (int j = 0; j < 16; ++j) { float d = x2v[j] - mean2; t2 += d * d; }
  t2 = wave_sum(t2);
  float rstd2 = 1.0f / sqrtf(t2 * (1.f / Cc) + 1e-5f);
#pragma unroll
  for (int c = 0; c < 4; ++c) {
    float4 t;
    t.x = x2v[c * 4 + 0]; t.y = x2v[c * 4 + 1]; t.z = x2v[c * 4 + 2]; t.w = x2v[c * 4 + 3];
    *(float4*)&xr[c * 256 + lane * 4] = t;
    short4v o;
#pragma unroll
    for (int j = 0; j < 4; ++j) {
      int idx = c * 256 + lane * 4 + j;
      ((short*)&o)[j] = (short)f2b((x2v[c * 4 + j] - mean2) * rstd2 * fg[idx] + fb[idx]);
    }
    *(short4v*)&h_ffn[(size_t)row * Cc + c * 256 + lane * 4] = o;
  }
}

}  // namespace

extern "C" void kernel_launch(void* const* d_in, const int* in_sizes, int n_in, void* d_out,
                              int out_size, void* d_ws, size_t ws_size, hipStream_t stream) {
  const float* x = (const float*)d_in[0];
  const float* ln_attn_g = (const float*)d_in[1];
  const float* ln_attn_b = (const float*)d_in[2];
  const float* qkv_w = (const float*)d_in[3];
  const float* out_w = (const float*)d_in[4];
  const float* head_scales = (const float*)d_in[5];
  const float* ln_hex_g = (const float*)d_in[6];
  const float* ln_hex_b = (const float*)d_in[7];
  const float* to_qd_w = (const float*)d_in[8];
  const float* from_qd_w = (const float*)d_in[9];
  const float* hex_scale = (const float*)d_in[10];
  const float* ln_ffn_g = (const float*)d_in[11];
  const float* ln_ffn_b = (const float*)d_in[12];
  const float* ffn_w1 = (const float*)d_in[13];
  const float* ffn_b1 = (const float*)d_in[14];
  const float* ffn_w2 = (const float*)d_in[15];
  const float* ffn_b2 = (const float*)d_in[16];

  char* ws = (char*)d_ws;
  size_t off = 0;
  auto alloc = [&](size_t bytes) -> char* {
    char* p = ws + off;
    off += (bytes + 255) & ~(size_t)255;
    return p;
  };
  // region A (50.33 MB): qkvh+qkvl; later gelu(33.55) + x1(16.78)
  char* regA = alloc((size_t)Mrows * 3 * Cc * 2 * 2);
  unsigned short* qkvh = (unsigned short*)regA;
  unsigned short* qkvl = qkvh + (size_t)Mrows * 3 * Cc;
  unsigned short* gelu = (unsigned short*)regA;                         // after attention
  float* x1 = (float*)(regA + (size_t)Mrows * FFNd * 2);                // after attention
  // region B (16.78 MB): h (fp32 LN out); later khsw+klsw
  char* regB = alloc((size_t)Mrows * Cc * 4);
  float* h = (float*)regB;
  unsigned short* khsw = (unsigned short*)regB;
  unsigned short* klsw = khsw + (size_t)Bb * Hh * Tt * 128;
  // region C (16.78 MB): vth+vtl; later w1_b+w2_b
  char* regC = alloc((size_t)Bb * Hh * Dd * Tt * 2 * 2);
  unsigned short* vth = (unsigned short*)regC;
  unsigned short* vtl = vth + (size_t)Bb * Hh * Dd * Tt;
  unsigned short* w1_b = (unsigned short*)regC;
  unsigned short* w2_b = w1_b + (size_t)FFNd * Cc;
  // region D (16.78 MB): attn_out fp32; later h_ffn bf16
  char* regD = alloc((size_t)Mrows * Cc * 4);
  float* attn_out = (float*)regD;
  unsigned short* h_ffn = (unsigned short*)regD;
  float* ct = (float*)alloc((size_t)Tt * 64 * 4);
  float* st = (float*)alloc((size_t)Tt * 64 * 4);
  float* qp = (float*)alloc((size_t)Bb * Hh * Tt * 4);
  float* kp = (float*)alloc((size_t)Bb * Hh * Tt * 4);

  // 1) LN(attn)
  ln_kernel<<<Mrows / 4, 256, 0, stream>>>(x, ln_attn_g, ln_attn_b, h);
  // 2) QKV GEMM (2-way split in, split-bf16 out)
  gemm_sp<2, 2><<<dim3(Mrows / 128, (3 * Cc) / 128), 256, 0, stream>>>(h, qkv_w, nullptr, qkvh,
                                                                       qkvl, nullptr, 3 * Cc, Cc);
  // 3) RoPE + K-swizzle + trigram projections
  rope_table<<<(Tt * 64) / 256, 256, 0, stream>>>(ct, st);
  rope_apply<<<(Bb * Hh * Tt) / 4, 256, 0, stream>>>(qkvh, qkvl, khsw, klsw, ct, st, qp, kp);
  // 4) V transpose
  vtrans<<<Bb * Hh * 32 * 2, 256, 0, stream>>>(qkvh, qkvl, vth, vtl);
  // 5) fused attention
  attn_fused<<<Bb * Hh * (Tt / 64), 256, 0, stream>>>(qkvh, qkvl, khsw, klsw, vth, vtl, qp, kp,
                                                      head_scales, attn_out);
  // 6) out-proj (3-way split) + residual -> x1
  gemm_sp<3, 1><<<dim3(Mrows / 128, Cc / 128), 256, 0, stream>>>(attn_out, out_w, x1, nullptr,
                                                                 nullptr, x, Cc, Cc);
  // 7) hexagram VQ + FFN LN prep (h_ffn overlays attn_out region)
  hex_kernel<<<Mrows / 4, 256, 0, stream>>>(x1, ln_hex_g, ln_hex_b, to_qd_w, from_qd_w, hex_scale,
                                            ln_ffn_g, ln_ffn_b, h_ffn);
  // 8) FFN weight casts (overlay vt region, dead after attention)
  cast_kernel<<<(FFNd * Cc) / 1024, 256, 0, stream>>>(ffn_w1, w1_b, FFNd * Cc);
  cast_kernel<<<(Cc * FFNd) / 1024, 256, 0, stream>>>(ffn_w2, w2_b, Cc * FFNd);
  // 9) FFN
  gemm_bt<2><<<dim3(Mrows / 128, FFNd / 128), 256, 0, stream>>>(h_ffn, w1_b, nullptr, gelu,
                                                                ffn_b1, nullptr, FFNd, Cc);
  gemm_bt<3><<<dim3(Mrows / 128, Cc / 128), 256, 0, stream>>>(gelu, w2_b, (float*)d_out, nullptr,
                                                              ffn_b2, x1, Cc, FFNd);
}

// Round 4
// 542.722 us; speedup vs baseline: 1.9953x; 1.2215x over previous
//
#include <hip/hip_runtime.h>
#include <hip/hip_bf16.h>

typedef __attribute__((ext_vector_type(4))) float f32x4;
typedef __attribute__((ext_vector_type(8))) short short8;
typedef __attribute__((ext_vector_type(4))) short short4v;

namespace {

constexpr int Tt = 2048, Cc = 1024, Hh = 8, Dd = 128, FFNd = 4096;
constexpr int Bb = 2;
constexpr int Mrows = Bb * Tt;  // 4096
constexpr float kNEG = -1e30f;
constexpr float L2E = 1.4426950408889634f;

static __device__ __forceinline__ float b2f(unsigned short u) {
  return __uint_as_float(((unsigned int)u) << 16);
}
static __device__ __forceinline__ unsigned short f2b(float f) {
  __hip_bfloat16 h = __float2bfloat16(f);
  unsigned short u;
  __builtin_memcpy(&u, &h, 2);
  return u;
}
static __device__ __forceinline__ void split2(float v, unsigned short& h, unsigned short& l) {
  h = f2b(v);
  float r = v - b2f(h);  // exact
  l = f2b(r);
}
static __device__ __forceinline__ void split3(float v, unsigned short& h, unsigned short& m,
                                              unsigned short& l) {
  h = f2b(v);
  float r = v - b2f(h);
  m = f2b(r);
  float r2 = r - b2f(m);
  l = f2b(r2);
}
static __device__ __forceinline__ float wave_sum(float v) {
#pragma unroll
  for (int m = 1; m < 64; m <<= 1) v += __shfl_xor(v, m);
  return v;
}

// ---------------- weight split kernels ----------------
__global__ __launch_bounds__(256) void cast_kernel(const float* __restrict__ in,
                                                   unsigned short* __restrict__ out, int n) {
  int i = (blockIdx.x * 256 + threadIdx.x) * 4;
  if (i + 3 < n) {
    float4 v = *(const float4*)&in[i];
    short4v o;
    o.x = (short)f2b(v.x); o.y = (short)f2b(v.y); o.z = (short)f2b(v.z); o.w = (short)f2b(v.w);
    *(short4v*)&out[i] = o;
  }
}
__global__ __launch_bounds__(256) void wsplit2_k(const float* __restrict__ in,
                                                 unsigned short* __restrict__ o0,
                                                 unsigned short* __restrict__ o1, int n) {
  int i = (blockIdx.x * 256 + threadIdx.x) * 4;
  if (i + 3 < n) {
    float4 v = *(const float4*)&in[i];
    short4v a, b;
#pragma unroll
    for (int j = 0; j < 4; ++j) {
      unsigned short hh, ll;
      split2(((float*)&v)[j], hh, ll);
      a[j] = (short)hh; b[j] = (short)ll;
    }
    *(short4v*)&o0[i] = a;
    *(short4v*)&o1[i] = b;
  }
}
__global__ __launch_bounds__(256) void wsplit3_k(const float* __restrict__ in,
                                                 unsigned short* __restrict__ o0,
                                                 unsigned short* __restrict__ o1,
                                                 unsigned short* __restrict__ o2, int n) {
  int i = (blockIdx.x * 256 + threadIdx.x) * 4;
  if (i + 3 < n) {
    float4 v = *(const float4*)&in[i];
    short4v a, b, c;
#pragma unroll
    for (int j = 0; j < 4; ++j) {
      unsigned short hh, mm, ll;
      split3(((float*)&v)[j], hh, mm, ll);
      a[j] = (short)hh; b[j] = (short)mm; c[j] = (short)ll;
    }
    *(short4v*)&o0[i] = a;
    *(short4v*)&o1[i] = b;
    *(short4v*)&o2[i] = c;
  }
}

// ---------------- LayerNorm fp32 -> split2 planes ----------------
__global__ __launch_bounds__(256) void ln_split(const float* __restrict__ x,
                                                const float* __restrict__ g,
                                                const float* __restrict__ bb,
                                                unsigned short* __restrict__ oh,
                                                unsigned short* __restrict__ ol) {
  int row = blockIdx.x * 4 + (threadIdx.x >> 6);
  int lane = threadIdx.x & 63;
  const float* xr = x + (size_t)row * Cc;
  float v[16];
  float s = 0.f;
#pragma unroll
  for (int c = 0; c < 4; ++c) {
    float4 t = *(const float4*)&xr[c * 256 + lane * 4];
    v[c * 4 + 0] = t.x; v[c * 4 + 1] = t.y; v[c * 4 + 2] = t.z; v[c * 4 + 3] = t.w;
    s += t.x + t.y + t.z + t.w;
  }
  s = wave_sum(s);
  float mean = s * (1.f / Cc);
  float s2 = 0.f;
#pragma unroll
  for (int j = 0; j < 16; ++j) { float d = v[j] - mean; s2 += d * d; }
  s2 = wave_sum(s2);
  float rstd = 1.0f / sqrtf(s2 * (1.f / Cc) + 1e-5f);
#pragma unroll
  for (int c = 0; c < 4; ++c) {
    short4v a, b;
#pragma unroll
    for (int j = 0; j < 4; ++j) {
      int idx = c * 256 + lane * 4 + j;
      float hv = (v[c * 4 + j] - mean) * rstd * g[idx] + bb[idx];
      unsigned short hh, ll;
      split2(hv, hh, ll);
      a[j] = (short)hh; b[j] = (short)ll;
    }
    *(short4v*)&oh[(size_t)row * Cc + c * 256 + lane * 4] = a;
    *(short4v*)&ol[(size_t)row * Cc + c * 256 + lane * 4] = b;
  }
}

// ---------------- multi-plane bf16 GEMM: C = A @ W^T ----------------
// NS=2: 3 passes (~2^-18). NS=3: 6 passes (~fp32). EPI 0: split2 planes out (QKV);
// EPI 1: fp32 + resid.
template <int NS, int EPI>
__global__ __launch_bounds__(256) void gemm_pn(
    const unsigned short* __restrict__ A0, const unsigned short* __restrict__ A1,
    const unsigned short* __restrict__ A2, const unsigned short* __restrict__ W0,
    const unsigned short* __restrict__ W1, const unsigned short* __restrict__ W2,
    unsigned short* __restrict__ outP, size_t planeStride, float* __restrict__ outF,
    const float* __restrict__ resid, int Nn, int Kk) {
  __shared__ __align__(16) unsigned short As[NS][128 * 32];
  __shared__ __align__(16) unsigned short Bs[NS][128 * 32];
  int m0 = blockIdx.x * 128, n0 = blockIdx.y * 128;
  int tid = threadIdx.x, lane = tid & 63, wid = tid >> 6;
  int wr = (wid >> 1) * 64, wc = (wid & 1) * 64;
  int g = lane >> 4, r16 = lane & 15;
  const unsigned short* Aps[3] = {A0, A1, A2};
  const unsigned short* Wps[3] = {W0, W1, W2};
  f32x4 acc[4][4];
#pragma unroll
  for (int mi = 0; mi < 4; ++mi)
#pragma unroll
    for (int ni = 0; ni < 4; ++ni) acc[mi][ni] = (f32x4){0.f, 0.f, 0.f, 0.f};
  for (int k0 = 0; k0 < Kk; k0 += 32) {
    __syncthreads();
#pragma unroll
    for (int s = 0; s < NS; ++s)
#pragma unroll
      for (int it = 0; it < 2; ++it) {
        int slot = it * 256 + tid;
        int row = slot >> 2, sw = slot & 3;
        int cc = sw ^ (row & 3);
        *(short8*)&As[s][slot * 8] = *(const short8*)&Aps[s][(size_t)(m0 + row) * Kk + k0 + cc * 8];
        *(short8*)&Bs[s][slot * 8] = *(const short8*)&Wps[s][(size_t)(n0 + row) * Kk + k0 + cc * 8];
      }
    __syncthreads();
    short8 af[NS][4], bfv[NS][4];
#pragma unroll
    for (int mi = 0; mi < 4; ++mi) {
      int row = wr + mi * 16 + r16;
      int so = row * 32 + ((g ^ (row & 3)) * 8);
#pragma unroll
      for (int s = 0; s < NS; ++s) af[s][mi] = *(short8*)&As[s][so];
    }
#pragma unroll
    for (int ni = 0; ni < 4; ++ni) {
      int row = wc + ni * 16 + r16;
      int so = row * 32 + ((g ^ (row & 3)) * 8);
#pragma unroll
      for (int s = 0; s < NS; ++s) bfv[s][ni] = *(short8*)&Bs[s][so];
    }
    __builtin_amdgcn_s_setprio(1);
#pragma unroll
    for (int mi = 0; mi < 4; ++mi)
#pragma unroll
      for (int ni = 0; ni < 4; ++ni) {
        f32x4 a = acc[mi][ni];
        if constexpr (NS == 3) {
          a = __builtin_amdgcn_mfma_f32_16x16x32_bf16(af[1][mi], bfv[1][ni], a, 0, 0, 0);
          a = __builtin_amdgcn_mfma_f32_16x16x32_bf16(af[0][mi], bfv[2][ni], a, 0, 0, 0);
          a = __builtin_amdgcn_mfma_f32_16x16x32_bf16(af[2][mi], bfv[0][ni], a, 0, 0, 0);
        }
        a = __builtin_amdgcn_mfma_f32_16x16x32_bf16(af[0][mi], bfv[1][ni], a, 0, 0, 0);
        a = __builtin_amdgcn_mfma_f32_16x16x32_bf16(af[1][mi], bfv[0][ni], a, 0, 0, 0);
        a = __builtin_amdgcn_mfma_f32_16x16x32_bf16(af[0][mi], bfv[0][ni], a, 0, 0, 0);
        acc[mi][ni] = a;
      }
    __builtin_amdgcn_s_setprio(0);
  }
#pragma unroll
  for (int mi = 0; mi < 4; ++mi)
#pragma unroll
    for (int ni = 0; ni < 4; ++ni)
#pragma unroll
      for (int r = 0; r < 4; ++r) {
        int row = m0 + wr + mi * 16 + 4 * g + r;
        int col = n0 + wc + ni * 16 + r16;
        float v = acc[mi][ni][r];
        if constexpr (EPI == 0) {
          int sec = col >> 10, cw = col & 1023;
          unsigned short hh, ll;
          split2(v, hh, ll);
          outP[(size_t)(2 * sec) * planeStride + (size_t)row * Cc + cw] = hh;
          outP[(size_t)(2 * sec + 1) * planeStride + (size_t)row * Cc + cw] = ll;
        } else {
          size_t o = (size_t)row * Nn + col;
          outF[o] = v + resid[o];
        }
      }
}

// ---------------- bf16 MFMA GEMM for FFN ----------------
template <int EPI>  // 2: +bias, GELU -> bf16 ; 3: +bias, +resid -> fp32
__global__ __launch_bounds__(256) void gemm_bt(const unsigned short* __restrict__ A,
                                               const unsigned short* __restrict__ W,
                                               float* __restrict__ outF,
                                               unsigned short* __restrict__ outB,
                                               const float* __restrict__ bias,
                                               const float* __restrict__ resid, int Nn, int Kk) {
  __shared__ __align__(16) unsigned short As[128 * 32];
  __shared__ __align__(16) unsigned short Bs[128 * 32];
  int m0 = blockIdx.x * 128, n0 = blockIdx.y * 128;
  int tid = threadIdx.x, lane = tid & 63, wid = tid >> 6;
  int wr = (wid >> 1) * 64, wc = (wid & 1) * 64;
  int g = lane >> 4, r16 = lane & 15;
  f32x4 acc[4][4];
#pragma unroll
  for (int mi = 0; mi < 4; ++mi)
#pragma unroll
    for (int ni = 0; ni < 4; ++ni) acc[mi][ni] = (f32x4){0.f, 0.f, 0.f, 0.f};
  for (int k0 = 0; k0 < Kk; k0 += 32) {
    __syncthreads();
#pragma unroll
    for (int c = 0; c < 2; ++c) {
      int chunk = tid + c * 256;
      int row = chunk >> 2, cc = chunk & 3;
      int sw = cc ^ (row & 3);
      *(short8*)&As[row * 32 + sw * 8] = *(const short8*)&A[(size_t)(m0 + row) * Kk + k0 + cc * 8];
      *(short8*)&Bs[row * 32 + sw * 8] = *(const short8*)&W[(size_t)(n0 + row) * Kk + k0 + cc * 8];
    }
    __syncthreads();
    short8 af[4], bfr[4];
#pragma unroll
    for (int mi = 0; mi < 4; ++mi) {
      int row = wr + mi * 16 + r16;
      af[mi] = *(short8*)&As[row * 32 + ((g ^ (row & 3)) * 8)];
    }
#pragma unroll
    for (int ni = 0; ni < 4; ++ni) {
      int row = wc + ni * 16 + r16;
      bfr[ni] = *(short8*)&Bs[row * 32 + ((g ^ (row & 3)) * 8)];
    }
    __builtin_amdgcn_s_setprio(1);
#pragma unroll
    for (int mi = 0; mi < 4; ++mi)
#pragma unroll
      for (int ni = 0; ni < 4; ++ni)
        acc[mi][ni] = __builtin_amdgcn_mfma_f32_16x16x32_bf16(af[mi], bfr[ni], acc[mi][ni], 0, 0, 0);
    __builtin_amdgcn_s_setprio(0);
  }
#pragma unroll
  for (int mi = 0; mi < 4; ++mi)
#pragma unroll
    for (int ni = 0; ni < 4; ++ni)
#pragma unroll
      for (int r = 0; r < 4; ++r) {
        int row = m0 + wr + mi * 16 + 4 * g + r;
        int col = n0 + wc + ni * 16 + r16;
        size_t o = (size_t)row * Nn + col;
        float v = acc[mi][ni][r];
        if constexpr (EPI == 2) {
          v += bias[col];
          v = 0.5f * v * (1.f + erff(v * 0.70710678118654752f));
          outB[o] = f2b(v);
        } else {
          v += bias[col];
          outF[o] = v + resid[o];
        }
      }
}

// ---------------- RoPE tables ----------------
__global__ __launch_bounds__(256) void rope_table(float* __restrict__ ct, float* __restrict__ st) {
  int idx = blockIdx.x * 256 + threadIdx.x;  // < T*64
  int t = idx >> 6, i = idx & 63;
  float e = (float)i * (1.f / 64.f);
  float p = powf(10000.0f, e);
  float inv = 1.0f / p;
  float ang = (float)t * inv;
  ct[idx] = cosf(ang);
  st[idx] = sinf(ang);
}

// ---------------- RoPE apply on q/k planes; K -> swizzled; qp/kp ----------------
__global__ __launch_bounds__(256) void rope_apply(unsigned short* __restrict__ qh_p,
                                                  unsigned short* __restrict__ ql_p,
                                                  const unsigned short* __restrict__ kh_p,
                                                  const unsigned short* __restrict__ kl_p,
                                                  unsigned short* __restrict__ khsw,
                                                  unsigned short* __restrict__ klsw,
                                                  const float* __restrict__ ct,
                                                  const float* __restrict__ st,
                                                  float* __restrict__ qp, float* __restrict__ kp) {
  int w = blockIdx.x * 4 + (threadIdx.x >> 6);  // (b,h,t)
  int lane = threadIdx.x & 63;
  int b = w / (Hh * Tt);
  int rem = w % (Hh * Tt);
  int h = rem / Tt;
  int t = rem % Tt;
  size_t base = (size_t)(b * Tt + t) * Cc + h * Dd;
  float cv = ct[t * 64 + lane], sv = st[t * 64 + lane];
  float q_lo = b2f(qh_p[base + lane]) + b2f(ql_p[base + lane]);
  float q_hi = b2f(qh_p[base + lane + 64]) + b2f(ql_p[base + lane + 64]);
  float qn_lo = q_lo * cv - q_hi * sv;
  float qn_hi = q_hi * cv + q_lo * sv;
  unsigned short hh, ll;
  split2(qn_lo, hh, ll);
  qh_p[base + lane] = hh; ql_p[base + lane] = ll;
  split2(qn_hi, hh, ll);
  qh_p[base + lane + 64] = hh; ql_p[base + lane + 64] = ll;
  float k_lo = b2f(kh_p[base + lane]) + b2f(kl_p[base + lane]);
  float k_hi = b2f(kh_p[base + lane + 64]) + b2f(kl_p[base + lane + 64]);
  float kn_lo = k_lo * cv - k_hi * sv;
  float kn_hi = k_hi * cv + k_lo * sv;
  size_t krow = ((size_t)(b * Hh + h) * Tt + t) * 128;
  int tsw = t & 7;
  int d0 = lane, d1 = lane + 64;
  int c0 = (((d0 >> 3) ^ tsw) << 3) | (d0 & 7);
  int c1 = (((d1 >> 3) ^ tsw) << 3) | (d1 & 7);
  split2(kn_lo, hh, ll);
  khsw[krow + c0] = hh; klsw[krow + c0] = ll;
  split2(kn_hi, hh, ll);
  khsw[krow + c1] = hh; klsw[krow + c1] = ll;
  float t0 = (((h >> 0) & 1) ? 1.f : -1.f) * 0.57735026918962576f;
  float t1 = (((h >> 1) & 1) ? 1.f : -1.f) * 0.57735026918962576f;
  float t2 = (((h >> 2) & 1) ? 1.f : -1.f) * 0.57735026918962576f;
  float q0v = __shfl(qn_lo, 0), q1v = __shfl(qn_lo, 1), q2v = __shfl(qn_lo, 2);
  float k0v = __shfl(kn_lo, 0), k1v = __shfl(kn_lo, 1), k2v = __shfl(kn_lo, 2);
  if (lane == 0) {
    qp[(size_t)(b * Hh + h) * Tt + t] = q0v * t0 + q1v * t1 + q2v * t2;
    kp[(size_t)(b * Hh + h) * Tt + t] = k0v * t0 + k1v * t1 + k2v * t2;
  }
}

// ---------------- V transpose: v planes -> vt[bh][d][t] ----------------
__global__ __launch_bounds__(256) void vtrans(const unsigned short* __restrict__ vh_p,
                                              const unsigned short* __restrict__ vl_p,
                                              unsigned short* __restrict__ vth,
                                              unsigned short* __restrict__ vtl) {
  __shared__ unsigned short Lh[64 * 68], Ll[64 * 68];
  int bidx = blockIdx.x;  // bh*64 + tt*2 + dd
  int dd = bidx & 1;
  int tt = (bidx >> 1) & 31;
  int bh = bidx >> 6;
  int b = bh >> 3, h = bh & 7;
  int tid = threadIdx.x;
#pragma unroll
  for (int it = 0; it < 2; ++it) {
    int chunk = tid + it * 256;  // 0..511
    int tr = chunk >> 3, c8 = chunk & 7;
    size_t src = (size_t)(b * Tt + tt * 64 + tr) * Cc + h * Dd + dd * 64 + c8 * 8;
    short8 vh = *(const short8*)&vh_p[src];
    short8 vl = *(const short8*)&vl_p[src];
    *(short4v*)&Lh[tr * 68 + c8 * 8] = *(short4v*)&vh;
    *(short4v*)&Lh[tr * 68 + c8 * 8 + 4] = *((short4v*)&vh + 1);
    *(short4v*)&Ll[tr * 68 + c8 * 8] = *(short4v*)&vl;
    *(short4v*)&Ll[tr * 68 + c8 * 8 + 4] = *((short4v*)&vl + 1);
  }
  __syncthreads();
#pragma unroll
  for (int it = 0; it < 2; ++it) {
    int chunk = tid + it * 256;
    int dr = chunk >> 3, t8 = chunk & 7;
    short8 oh, ol;
#pragma unroll
    for (int e = 0; e < 8; ++e) {
      oh[e] = (short)Lh[(t8 * 8 + e) * 68 + dr];
      ol[e] = (short)Ll[(t8 * 8 + e) * 68 + dr];
    }
    size_t dst = (size_t)(bh * Dd + dd * 64 + dr) * Tt + tt * 64 + t8 * 8;
    *(short8*)&vth[dst] = oh;
    *(short8*)&vtl[dst] = ol;
  }
}

// ---------------- fused causal flash attention v3 (transposed-S, no P round-trip) ------
__global__ __launch_bounds__(256, 2) void attn_v3(
    const unsigned short* __restrict__ qh_p, const unsigned short* __restrict__ ql_p,
    const unsigned short* __restrict__ khsw, const unsigned short* __restrict__ klsw,
    const unsigned short* __restrict__ vth, const unsigned short* __restrict__ vtl,
    const float* __restrict__ qp, const float* __restrict__ kp,
    const float* __restrict__ head_scales, unsigned short* __restrict__ ao0,
    unsigned short* __restrict__ ao1, unsigned short* __restrict__ ao2) {
  int cix = blockIdx.x & 255, rix = blockIdx.x >> 8;
  int bh = cix >> 4, ii = cix & 15;
  int qblk = rix ? ii : 31 - ii;  // pairs (31-i, i): per-CU work uniform (68 tiles)
  int b = bh >> 3, h = bh & 7;
  int q0 = qblk * 64;
  int tid = threadIdx.x, lane = tid & 63, wid = tid >> 6;
  int wq0 = q0 + wid * 16;
  int g = lane >> 4, r16 = lane & 15;
  __shared__ __align__(16) unsigned short Ksh[32 * 128], Ksl[32 * 128];
  __shared__ __align__(16) unsigned short Vsh[128 * 34], Vsl[128 * 34];

  short8 qfh[4], qfl[4];
#pragma unroll
  for (int c4 = 0; c4 < 4; ++c4) {
    size_t qoff = (size_t)(b * Tt + wq0 + r16) * Cc + h * Dd + c4 * 32 + g * 8;
    qfh[c4] = *(const short8*)&qh_p[qoff];
    qfl[c4] = *(const short8*)&ql_p[qoff];
  }
  float hs = head_scales[h];
  const float* kpb = kp + (size_t)bh * Tt;
  float qpl2 = qp[(size_t)bh * Tt + wq0 + r16] * L2E;  // per-lane query proj (log2 dom)

  const unsigned short* Khb = khsw + (size_t)bh * Tt * 128;
  const unsigned short* Klb = klsw + (size_t)bh * Tt * 128;
  const unsigned short* Vhb = vth + (size_t)bh * Dd * Tt;
  const unsigned short* Vlb = vtl + (size_t)bh * Dd * Tt;

  f32x4 accA[8], accG[8];
#pragma unroll
  for (int n = 0; n < 8; ++n) {
    accA[n] = (f32x4){0.f, 0.f, 0.f, 0.f};
    accG[n] = (f32x4){0.f, 0.f, 0.f, 0.f};
  }
  float m1 = kNEG, l1 = 0.f, m2 = kNEG, l2 = 0.f;  // per-lane (query r16) stats
  const float scale2 = 0.08838834764831845f * L2E;

  int nt = 2 * qblk + 2;
  // stage registers (T14: issue next-tile loads before compute)
  short8 rkh[2], rkl[2], rvh[2], rvl[2];
  int krw[2], kcl[2], vdd[2], vkk[2];
#pragma unroll
  for (int it = 0; it < 2; ++it) {
    int chunk = tid + it * 256;
    krw[it] = chunk >> 4; kcl[it] = (chunk & 15) * 8;
    vdd[it] = chunk >> 2; vkk[it] = (chunk & 3) * 8;
  }
  auto LOADT = [&](int s0) {
#pragma unroll
    for (int it = 0; it < 2; ++it) {
      size_t ksrc = (size_t)(s0 + krw[it]) * 128 + kcl[it];
      rkh[it] = *(const short8*)&Khb[ksrc];
      rkl[it] = *(const short8*)&Klb[ksrc];
      size_t vsrc = (size_t)vdd[it] * Tt + s0 + vkk[it];
      rvh[it] = *(const short8*)&Vhb[vsrc];
      rvl[it] = *(const short8*)&Vlb[vsrc];
    }
  };
  LOADT(0);
  for (int t = 0; t < nt; ++t) {
    int s0 = t * 32;
    __syncthreads();  // previous tile fully read
#pragma unroll
    for (int it = 0; it < 2; ++it) {
      *(short8*)&Ksh[krw[it] * 128 + kcl[it]] = rkh[it];
      *(short8*)&Ksl[krw[it] * 128 + kcl[it]] = rkl[it];
      *(short8*)&Vsh[vdd[it] * 34 + vkk[it]] = rvh[it];
      *(short8*)&Vsl[vdd[it] * 34 + vkk[it]] = rvl[it];
    }
    __syncthreads();  // tile ready
    if (t + 1 < nt) LOADT(s0 + 32);  // overlap next loads with compute
    if (s0 > wq0 + 15) continue;
    float kpv[2][4];
#pragma unroll
    for (int st2 = 0; st2 < 2; ++st2)
#pragma unroll
      for (int rr = 0; rr < 4; ++rr) kpv[st2][rr] = kpb[s0 + st2 * 16 + 4 * g + rr];
    // S^T = K·Q^T: lane (g,r16) holds S[query r16][key s0+st2*16+4g+rr]
    f32x4 sf[2];
    sf[0] = (f32x4){0.f, 0.f, 0.f, 0.f};
    sf[1] = (f32x4){0.f, 0.f, 0.f, 0.f};
    __builtin_amdgcn_s_setprio(1);
#pragma unroll
    for (int st2 = 0; st2 < 2; ++st2) {
      int row = st2 * 16 + r16, rsw = row & 7;
#pragma unroll
      for (int c4 = 0; c4 < 4; ++c4) {
        int off = row * 128 + (((c4 * 4 + g) ^ rsw) * 8);
        short8 kh8 = *(short8*)&Ksh[off];
        short8 kl8 = *(short8*)&Ksl[off];
        sf[st2] = __builtin_amdgcn_mfma_f32_16x16x32_bf16(kl8, qfh[c4], sf[st2], 0, 0, 0);
        sf[st2] = __builtin_amdgcn_mfma_f32_16x16x32_bf16(kh8, qfl[c4], sf[st2], 0, 0, 0);
        sf[st2] = __builtin_amdgcn_mfma_f32_16x16x32_bf16(kh8, qfh[c4], sf[st2], 0, 0, 0);
      }
    }
    __builtin_amdgcn_s_setprio(0);
    // causal mask + dual online softmax (log2 domain); reduce over 4-lane query group
    bool okf[2][4];
    float sv[2][4], gvv[2][4];
    float mx = kNEG, gmx = kNEG;
#pragma unroll
    for (int st2 = 0; st2 < 2; ++st2)
#pragma unroll
      for (int rr = 0; rr < 4; ++rr) {
        int key = s0 + st2 * 16 + 4 * g + rr;
        bool ok = key <= wq0 + r16;
        okf[st2][rr] = ok;
        float s = ok ? sf[st2][rr] * scale2 : kNEG;
        sv[st2][rr] = s;
        mx = fmaxf(mx, s);
        float gg = ok ? qpl2 * kpv[st2][rr] : kNEG;
        gvv[st2][rr] = gg;
        gmx = fmaxf(gmx, gg);
      }
    mx = fmaxf(mx, __shfl_xor(mx, 16));
    mx = fmaxf(mx, __shfl_xor(mx, 32));
    gmx = fmaxf(gmx, __shfl_xor(gmx, 16));
    gmx = fmaxf(gmx, __shfl_xor(gmx, 32));
    float mn = fmaxf(m1, mx), sc = exp2f(m1 - mn);
    float mg = fmaxf(m2, gmx), sg = exp2f(m2 - mg);
    float pa[2][4], pgv[2][4];
    float ps = 0.f, pgs = 0.f;
#pragma unroll
    for (int st2 = 0; st2 < 2; ++st2)
#pragma unroll
      for (int rr = 0; rr < 4; ++rr) {
        float p = okf[st2][rr] ? exp2f(sv[st2][rr] - mn) : 0.f;
        pa[st2][rr] = p; ps += p;
        float pq = okf[st2][rr] ? exp2f(gvv[st2][rr] - mg) : 0.f;
        pgv[st2][rr] = pq; pgs += pq;
      }
    ps += __shfl_xor(ps, 16); ps += __shfl_xor(ps, 32);
    pgs += __shfl_xor(pgs, 16); pgs += __shfl_xor(pgs, 32);
    l1 = l1 * sc + ps; m1 = mn;
    l2 = l2 * sg + pgs; m2 = mg;
    // broadcast rescale factors to D-layout rows (query 4g+rr)
    float sclA[4], sclG[4];
#pragma unroll
    for (int rr = 0; rr < 4; ++rr) {
      sclA[rr] = __shfl(sc, 4 * g + rr);
      sclG[rr] = __shfl(sg, 4 * g + rr);
    }
#pragma unroll
    for (int n = 0; n < 8; ++n)
#pragma unroll
      for (int rr = 0; rr < 4; ++rr) {
        accA[n][rr] *= sclA[rr];
        accG[n][rr] *= sclG[rr];
      }
    // pack P directly as A-fragment via key permutation κ(g,e)=(e>>2)*16+4g+(e&3)
    short8 pAh, pAl, pGh, pGl;
#pragma unroll
    for (int e = 0; e < 8; ++e) {
      unsigned short hh, ll;
      split2(pa[e >> 2][e & 3], hh, ll);
      pAh[e] = (short)hh; pAl[e] = (short)ll;
      split2(pgv[e >> 2][e & 3], hh, ll);
      pGh[e] = (short)hh; pGl[e] = (short)ll;
    }
    // PV: B-fragment = V[κ(g,e)][d] (two 4-key runs per lane)
    __builtin_amdgcn_s_setprio(1);
#pragma unroll
    for (int n = 0; n < 8; ++n) {
      int dofs = (n * 16 + r16) * 34;
      short8 vh8, vl8;
      *(short4v*)&vh8 = *(short4v*)&Vsh[dofs + 4 * g];
      *((short4v*)&vh8 + 1) = *(short4v*)&Vsh[dofs + 16 + 4 * g];
      *(short4v*)&vl8 = *(short4v*)&Vsl[dofs + 4 * g];
      *((short4v*)&vl8 + 1) = *(short4v*)&Vsl[dofs + 16 + 4 * g];
      accA[n] = __builtin_amdgcn_mfma_f32_16x16x32_bf16(pAl, vh8, accA[n], 0, 0, 0);
      accA[n] = __builtin_amdgcn_mfma_f32_16x16x32_bf16(pAh, vl8, accA[n], 0, 0, 0);
      accA[n] = __builtin_amdgcn_mfma_f32_16x16x32_bf16(pAh, vh8, accA[n], 0, 0, 0);
      accG[n] = __builtin_amdgcn_mfma_f32_16x16x32_bf16(pGl, vh8, accG[n], 0, 0, 0);
      accG[n] = __builtin_amdgcn_mfma_f32_16x16x32_bf16(pGh, vl8, accG[n], 0, 0, 0);
      accG[n] = __builtin_amdgcn_mfma_f32_16x16x32_bf16(pGh, vh8, accG[n], 0, 0, 0);
    }
    __builtin_amdgcn_s_setprio(0);
  }
  // epilogue: fetch l for query 4g+rr, combine, split3 to planes
  float lA[4], lG[4];
#pragma unroll
  for (int rr = 0; rr < 4; ++rr) {
    lA[rr] = __shfl(l1, 4 * g + rr);
    lG[rr] = __shfl(l2, 4 * g + rr);
  }
#pragma unroll
  for (int n = 0; n < 8; ++n)
#pragma unroll
    for (int rr = 0; rr < 4; ++rr) {
      int qi = wq0 + 4 * g + rr;
      float av = accA[n][rr] / lA[rr];
      float gq = accG[n][rr] / lG[rr];
      float o = av + hs * (gq - av);
      unsigned short s1, s2v, s3;
      split3(o, s1, s2v, s3);
      size_t oo = (size_t)(b * Tt + qi) * Cc + h * Dd + n * 16 + r16;
      ao0[oo] = s1; ao1[oo] = s2v; ao2[oo] = s3;
    }
}

// ---------------- hexagram VQ + FFN-LN prep ----------------
__global__ __launch_bounds__(256) void hex_kernel(float* __restrict__ x1,
                                                  const float* __restrict__ hg,
                                                  const float* __restrict__ hb,
                                                  const float* __restrict__ to_qd,
                                                  const float* __restrict__ from_qd,
                                                  const float* __restrict__ hex_scale,
                                                  const float* __restrict__ fg,
                                                  const float* __restrict__ fb,
                                                  unsigned short* __restrict__ h_ffn) {
  int row = blockIdx.x * 4 + (threadIdx.x >> 6);
  int lane = threadIdx.x & 63;
  float* xr = x1 + (size_t)row * Cc;
  float v[16];
  float s = 0.f;
#pragma unroll
  for (int c = 0; c < 4; ++c) {
    float4 t = *(const float4*)&xr[c * 256 + lane * 4];
    v[c * 4 + 0] = t.x; v[c * 4 + 1] = t.y; v[c * 4 + 2] = t.z; v[c * 4 + 3] = t.w;
    s += t.x + t.y + t.z + t.w;
  }
  s = wave_sum(s);
  float mean = s * (1.f / Cc);
  float s2 = 0.f;
#pragma unroll
  for (int j = 0; j < 16; ++j) { float d = v[j] - mean; s2 += d * d; }
  s2 = wave_sum(s2);
  float rstd = 1.0f / sqrtf(s2 * (1.f / Cc) + 1e-5f);
  float zq[6] = {0.f, 0.f, 0.f, 0.f, 0.f, 0.f};
#pragma unroll
  for (int c = 0; c < 4; ++c)
#pragma unroll
    for (int j2 = 0; j2 < 4; ++j2) {
      int idx = c * 256 + lane * 4 + j2;
      float hv = (v[c * 4 + j2] - mean) * rstd * hg[idx] + hb[idx];
#pragma unroll
      for (int j = 0; j < 6; ++j) zq[j] += hv * to_qd[j * Cc + idx];
    }
#pragma unroll
  for (int j = 0; j < 6; ++j) zq[j] = wave_sum(zq[j]);
  float hsc = hex_scale[0];
  float hard[6];
#pragma unroll
  for (int j = 0; j < 6; ++j) hard[j] = (zq[j] >= 0.f) ? hsc : -hsc;
  float x2v[16];
  float t1 = 0.f;
#pragma unroll
  for (int c = 0; c < 4; ++c)
#pragma unroll
    for (int j2 = 0; j2 < 4; ++j2) {
      int idx = c * 256 + lane * 4 + j2;
      float a = 0.f;
#pragma unroll
      for (int j = 0; j < 6; ++j) a += hard[j] * from_qd[idx * 6 + j];
      float xv = v[c * 4 + j2] + a;
      x2v[c * 4 + j2] = xv;
      t1 += xv;
    }
  t1 = wave_sum(t1);
  float mean2 = t1 * (1.f / Cc);
  float t2 = 0.f;
#pragma unroll
  for (int j = 0; j < 16; ++j) { float d = x2v[j] - mean2; t2 += d * d; }
  t2 = wave_sum(t2);
  float rstd2 = 1.0f / sqrtf(t2 * (1.f / Cc) + 1e-5f);
#pragma unroll
  for (int c = 0; c < 4; ++c) {
    float4 t;
    t.x = x2v[c * 4 + 0]; t.y = x2v[c * 4 + 1]; t.z = x2v[c * 4 + 2]; t.w = x2v[c * 4 + 3];
    *(float4*)&xr[c * 256 + lane * 4] = t;
    short4v o;
#pragma unroll
    for (int j = 0; j < 4; ++j) {
      int idx = c * 256 + lane * 4 + j;
      ((short*)&o)[j] = (short)f2b((x2v[c * 4 + j] - mean2) * rstd2 * fg[idx] + fb[idx]);
    }
    *(short4v*)&h_ffn[(size_t)row * Cc + c * 256 + lane * 4] = o;
  }
}

}  // namespace

extern "C" void kernel_launch(void* const* d_in, const int* in_sizes, int n_in, void* d_out,
                              int out_size, void* d_ws, size_t ws_size, hipStream_t stream) {
  const float* x = (const float*)d_in[0];
  const float* ln_attn_g = (const float*)d_in[1];
  const float* ln_attn_b = (const float*)d_in[2];
  const float* qkv_w = (const float*)d_in[3];
  const float* out_w = (const float*)d_in[4];
  const float* head_scales = (const float*)d_in[5];
  const float* ln_hex_g = (const float*)d_in[6];
  const float* ln_hex_b = (const float*)d_in[7];
  const float* to_qd_w = (const float*)d_in[8];
  const float* from_qd_w = (const float*)d_in[9];
  const float* hex_scale = (const float*)d_in[10];
  const float* ln_ffn_g = (const float*)d_in[11];
  const float* ln_ffn_b = (const float*)d_in[12];
  const float* ffn_w1 = (const float*)d_in[13];
  const float* ffn_b1 = (const float*)d_in[14];
  const float* ffn_w2 = (const float*)d_in[15];
  const float* ffn_b2 = (const float*)d_in[16];

  unsigned short* ws16 = (unsigned short*)d_ws;
  const size_t PL = (size_t)Mrows * Cc;  // 4,194,304 elems = 8 MB per plane
  unsigned short* hh = ws16 + 0 * PL;    // LN hi   -> later ao0
  unsigned short* hl = ws16 + 1 * PL;    // LN lo   -> later ao1
  unsigned short* qhp = ws16 + 2 * PL;   // Q hi    -> later w1b
  unsigned short* qlp = ws16 + 3 * PL;   // Q lo    -> later w2b
  unsigned short* khp = ws16 + 4 * PL;   // K hi    -> later ao2
  unsigned short* klp = ws16 + 5 * PL;   // K lo    -> later x1 (with vhp)
  unsigned short* vhp = ws16 + 6 * PL;   // V hi
  unsigned short* vlp = ws16 + 7 * PL;   // V lo    -> later h_ffn
  unsigned short* khsw = ws16 + 8 * PL;  // -> later ow planes / gelu (4 planes)
  unsigned short* klsw = ws16 + 9 * PL;
  unsigned short* vth = ws16 + 10 * PL;  // first: wqh
  unsigned short* vtl = ws16 + 11 * PL;  // first: wql
  float* tail = (float*)(ws16 + 12 * PL);
  float* ct = tail;
  float* st = ct + (size_t)Tt * 64;
  float* qp = st + (size_t)Tt * 64;
  float* kp = qp + (size_t)Bb * Hh * Tt;
  // aliases
  unsigned short* ao0 = hh;
  unsigned short* ao1 = hl;
  unsigned short* ao2 = khp;
  float* x1 = (float*)klp;  // spans klp+vhp (16.78 MB fp32)
  unsigned short* h_ffn = vlp;
  unsigned short* w1b = qhp;
  unsigned short* w2b = qlp;
  unsigned short* gelu = khsw;  // spans khsw..vtl (33.55 MB)
  unsigned short* wqh = vth;
  unsigned short* wql = vtl;
  unsigned short* ow0 = khsw;
  unsigned short* ow1 = khsw + (size_t)Cc * Cc;
  unsigned short* ow2 = khsw + (size_t)2 * Cc * Cc;

  // 1) LN(attn) -> split2 planes
  ln_split<<<Mrows / 4, 256, 0, stream>>>(x, ln_attn_g, ln_attn_b, hh, hl);
  // 2) qkv_w pre-split
  wsplit2_k<<<(3 * Cc * Cc) / 1024, 256, 0, stream>>>(qkv_w, wqh, wql, 3 * Cc * Cc);
  // 3) QKV GEMM (3-pass) -> q/k/v split2 planes
  gemm_pn<2, 0><<<dim3(Mrows / 128, (3 * Cc) / 128), 256, 0, stream>>>(
      hh, hl, nullptr, wqh, wql, nullptr, qhp, PL, nullptr, nullptr, 3 * Cc, Cc);
  // 4) RoPE + K-swizzle + trigram projections
  rope_table<<<(Tt * 64) / 256, 256, 0, stream>>>(ct, st);
  rope_apply<<<(Bb * Hh * Tt) / 4, 256, 0, stream>>>(qhp, qlp, khp, klp, khsw, klsw, ct, st, qp,
                                                     kp);
  // 5) V transpose (overwrites wqh/wql — dead)
  vtrans<<<Bb * Hh * 32 * 2, 256, 0, stream>>>(vhp, vlp, vth, vtl);
  // 6) fused attention -> split3 attn planes
  attn_v3<<<512, 256, 0, stream>>>(qhp, qlp, khsw, klsw, vth, vtl, qp, kp, head_scales, ao0, ao1,
                                   ao2);
  // 7) out_w pre-split (khsw dead)
  wsplit3_k<<<(Cc * Cc) / 1024, 256, 0, stream>>>(out_w, ow0, ow1, ow2, Cc * Cc);
  // 8) out-proj (6-pass) + residual -> x1
  gemm_pn<3, 1><<<dim3(Mrows / 128, Cc / 128), 256, 0, stream>>>(
      ao0, ao1, ao2, ow0, ow1, ow2, nullptr, 0, x1, x, Cc, Cc);
  // 9) hexagram VQ + FFN LN prep
  hex_kernel<<<Mrows / 4, 256, 0, stream>>>(x1, ln_hex_g, ln_hex_b, to_qd_w, from_qd_w, hex_scale,
                                            ln_ffn_g, ln_ffn_b, h_ffn);
  // 10) FFN weight casts (q planes dead)
  cast_kernel<<<(FFNd * Cc) / 1024, 256, 0, stream>>>(ffn_w1, w1b, FFNd * Cc);
  cast_kernel<<<(Cc * FFNd) / 1024, 256, 0, stream>>>(ffn_w2, w2b, Cc * FFNd);
  // 11) FFN
  gemm_bt<2><<<dim3(Mrows / 128, FFNd / 128), 256, 0, stream>>>(h_ffn, w1b, nullptr, gelu, ffn_b1,
                                                                nullptr, FFNd, Cc);
  gemm_bt<3><<<dim3(Mrows / 128, Cc / 128), 256, 0, stream>>>(gelu, w2b, (float*)d_out, nullptr,
                                                              ffn_b2, x1, Cc, FFNd);
}

// Round 5
// 530.923 us; speedup vs baseline: 2.0397x; 1.0222x over previous
//
#include <hip/hip_runtime.h>
#include <hip/hip_bf16.h>

typedef __attribute__((ext_vector_type(4))) float f32x4;
typedef __attribute__((ext_vector_type(8))) short short8;
typedef __attribute__((ext_vector_type(4))) short short4v;

namespace {

constexpr int Tt = 2048, Cc = 1024, Hh = 8, Dd = 128, FFNd = 4096;
constexpr int Bb = 2;
constexpr int Mrows = Bb * Tt;  // 4096
constexpr float kNEG = -1e30f;
constexpr float L2E = 1.4426950408889634f;

static __device__ __forceinline__ float b2f(unsigned short u) {
  return __uint_as_float(((unsigned int)u) << 16);
}
static __device__ __forceinline__ unsigned short f2b(float f) {
  __hip_bfloat16 h = __float2bfloat16(f);
  unsigned short u;
  __builtin_memcpy(&u, &h, 2);
  return u;
}
static __device__ __forceinline__ void split2(float v, unsigned short& h, unsigned short& l) {
  h = f2b(v);
  float r = v - b2f(h);  // exact
  l = f2b(r);
}
static __device__ __forceinline__ void split3(float v, unsigned short& h, unsigned short& m,
                                              unsigned short& l) {
  h = f2b(v);
  float r = v - b2f(h);
  m = f2b(r);
  float r2 = r - b2f(m);
  l = f2b(r2);
}
static __device__ __forceinline__ float wave_sum(float v) {
#pragma unroll
  for (int m = 1; m < 64; m <<= 1) v += __shfl_xor(v, m);
  return v;
}
// async global->LDS, 16B per lane; lds dst must be wave-uniform base (+ lane*16 implicit)
static __device__ __forceinline__ void gl16(const unsigned short* g, unsigned short* l) {
  __builtin_amdgcn_global_load_lds((const __attribute__((address_space(1))) void*)g,
                                   (__attribute__((address_space(3))) void*)l, 16, 0, 0);
}

// ---------------- weight split kernels ----------------
__global__ __launch_bounds__(256) void cast_kernel(const float* __restrict__ in,
                                                   unsigned short* __restrict__ out, int n) {
  int i = (blockIdx.x * 256 + threadIdx.x) * 4;
  if (i + 3 < n) {
    float4 v = *(const float4*)&in[i];
    short4v o;
    o.x = (short)f2b(v.x); o.y = (short)f2b(v.y); o.z = (short)f2b(v.z); o.w = (short)f2b(v.w);
    *(short4v*)&out[i] = o;
  }
}
__global__ __launch_bounds__(256) void wsplit2_k(const float* __restrict__ in,
                                                 unsigned short* __restrict__ o0,
                                                 unsigned short* __restrict__ o1, int n) {
  int i = (blockIdx.x * 256 + threadIdx.x) * 4;
  if (i + 3 < n) {
    float4 v = *(const float4*)&in[i];
    short4v a, b;
#pragma unroll
    for (int j = 0; j < 4; ++j) {
      unsigned short hh, ll;
      split2(((float*)&v)[j], hh, ll);
      a[j] = (short)hh; b[j] = (short)ll;
    }
    *(short4v*)&o0[i] = a;
    *(short4v*)&o1[i] = b;
  }
}
__global__ __launch_bounds__(256) void wsplit3_k(const float* __restrict__ in,
                                                 unsigned short* __restrict__ o0,
                                                 unsigned short* __restrict__ o1,
                                                 unsigned short* __restrict__ o2, int n) {
  int i = (blockIdx.x * 256 + threadIdx.x) * 4;
  if (i + 3 < n) {
    float4 v = *(const float4*)&in[i];
    short4v a, b, c;
#pragma unroll
    for (int j = 0; j < 4; ++j) {
      unsigned short hh, mm, ll;
      split3(((float*)&v)[j], hh, mm, ll);
      a[j] = (short)hh; b[j] = (short)mm; c[j] = (short)ll;
    }
    *(short4v*)&o0[i] = a;
    *(short4v*)&o1[i] = b;
    *(short4v*)&o2[i] = c;
  }
}

// ---------------- LayerNorm fp32 -> split2 planes ----------------
__global__ __launch_bounds__(256) void ln_split(const float* __restrict__ x,
                                                const float* __restrict__ g,
                                                const float* __restrict__ bb,
                                                unsigned short* __restrict__ oh,
                                                unsigned short* __restrict__ ol) {
  int row = blockIdx.x * 4 + (threadIdx.x >> 6);
  int lane = threadIdx.x & 63;
  const float* xr = x + (size_t)row * Cc;
  float v[16];
  float s = 0.f;
#pragma unroll
  for (int c = 0; c < 4; ++c) {
    float4 t = *(const float4*)&xr[c * 256 + lane * 4];
    v[c * 4 + 0] = t.x; v[c * 4 + 1] = t.y; v[c * 4 + 2] = t.z; v[c * 4 + 3] = t.w;
    s += t.x + t.y + t.z + t.w;
  }
  s = wave_sum(s);
  float mean = s * (1.f / Cc);
  float s2 = 0.f;
#pragma unroll
  for (int j = 0; j < 16; ++j) { float d = v[j] - mean; s2 += d * d; }
  s2 = wave_sum(s2);
  float rstd = 1.0f / sqrtf(s2 * (1.f / Cc) + 1e-5f);
#pragma unroll
  for (int c = 0; c < 4; ++c) {
    short4v a, b;
#pragma unroll
    for (int j = 0; j < 4; ++j) {
      int idx = c * 256 + lane * 4 + j;
      float hv = (v[c * 4 + j] - mean) * rstd * g[idx] + bb[idx];
      unsigned short hh, ll;
      split2(hv, hh, ll);
      a[j] = (short)hh; b[j] = (short)ll;
    }
    *(short4v*)&oh[(size_t)row * Cc + c * 256 + lane * 4] = a;
    *(short4v*)&ol[(size_t)row * Cc + c * 256 + lane * 4] = b;
  }
}

// ---------------- multi-plane bf16 GEMM: C = A @ W^T (global_load_lds staging) -------
// NS=2: 3 passes (~2^-18). NS=3: 6 passes (~fp32). EPI 0: split2 planes out (QKV);
// EPI 1: fp32 + resid.
template <int NS, int EPI>
__global__ __launch_bounds__(256) void gemm_pn(
    const unsigned short* __restrict__ A0, const unsigned short* __restrict__ A1,
    const unsigned short* __restrict__ A2, const unsigned short* __restrict__ W0,
    const unsigned short* __restrict__ W1, const unsigned short* __restrict__ W2,
    unsigned short* __restrict__ outP, size_t planeStride, float* __restrict__ outF,
    const float* __restrict__ resid, int Nn, int Kk) {
  __shared__ __align__(16) unsigned short As[NS][128 * 32];
  __shared__ __align__(16) unsigned short Bs[NS][128 * 32];
  int m0 = blockIdx.x * 128, n0 = blockIdx.y * 128;
  int tid = threadIdx.x, lane = tid & 63, wid = tid >> 6;
  int wr = (wid >> 1) * 64, wc = (wid & 1) * 64;
  int g = lane >> 4, r16 = lane & 15;
  const unsigned short* Aps[3] = {A0, A1, A2};
  const unsigned short* Wps[3] = {W0, W1, W2};
  // staging descriptors: pre-swizzled SOURCE + linear LDS dst => swizzled LDS image
  int srow[2], scc[2], sbase[2];
#pragma unroll
  for (int i = 0; i < 2; ++i) {
    int chunkbase = (wid * 2 + i) * 64;
    int chunk = chunkbase + lane;
    int row = chunk >> 2, sw = chunk & 3;
    srow[i] = row;
    scc[i] = (sw ^ (row & 3)) * 8;
    sbase[i] = chunkbase * 8;
  }
  f32x4 acc[4][4];
#pragma unroll
  for (int mi = 0; mi < 4; ++mi)
#pragma unroll
    for (int ni = 0; ni < 4; ++ni) acc[mi][ni] = (f32x4){0.f, 0.f, 0.f, 0.f};
  for (int k0 = 0; k0 < Kk; k0 += 32) {
    __syncthreads();
#pragma unroll
    for (int s = 0; s < NS; ++s)
#pragma unroll
      for (int i = 0; i < 2; ++i) {
        gl16(&Aps[s][(size_t)(m0 + srow[i]) * Kk + k0 + scc[i]], &As[s][sbase[i]]);
        gl16(&Wps[s][(size_t)(n0 + srow[i]) * Kk + k0 + scc[i]], &Bs[s][sbase[i]]);
      }
    __syncthreads();
    short8 af[NS][4], bfv[NS][4];
#pragma unroll
    for (int mi = 0; mi < 4; ++mi) {
      int row = wr + mi * 16 + r16;
      int so = row * 32 + ((g ^ (row & 3)) * 8);
#pragma unroll
      for (int s = 0; s < NS; ++s) af[s][mi] = *(short8*)&As[s][so];
    }
#pragma unroll
    for (int ni = 0; ni < 4; ++ni) {
      int row = wc + ni * 16 + r16;
      int so = row * 32 + ((g ^ (row & 3)) * 8);
#pragma unroll
      for (int s = 0; s < NS; ++s) bfv[s][ni] = *(short8*)&Bs[s][so];
    }
    __builtin_amdgcn_s_setprio(1);
#pragma unroll
    for (int mi = 0; mi < 4; ++mi)
#pragma unroll
      for (int ni = 0; ni < 4; ++ni) {
        f32x4 a = acc[mi][ni];
        if constexpr (NS == 3) {
          a = __builtin_amdgcn_mfma_f32_16x16x32_bf16(af[1][mi], bfv[1][ni], a, 0, 0, 0);
          a = __builtin_amdgcn_mfma_f32_16x16x32_bf16(af[0][mi], bfv[2][ni], a, 0, 0, 0);
          a = __builtin_amdgcn_mfma_f32_16x16x32_bf16(af[2][mi], bfv[0][ni], a, 0, 0, 0);
        }
        a = __builtin_amdgcn_mfma_f32_16x16x32_bf16(af[0][mi], bfv[1][ni], a, 0, 0, 0);
        a = __builtin_amdgcn_mfma_f32_16x16x32_bf16(af[1][mi], bfv[0][ni], a, 0, 0, 0);
        a = __builtin_amdgcn_mfma_f32_16x16x32_bf16(af[0][mi], bfv[0][ni], a, 0, 0, 0);
        acc[mi][ni] = a;
      }
    __builtin_amdgcn_s_setprio(0);
  }
#pragma unroll
  for (int mi = 0; mi < 4; ++mi)
#pragma unroll
    for (int ni = 0; ni < 4; ++ni)
#pragma unroll
      for (int r = 0; r < 4; ++r) {
        int row = m0 + wr + mi * 16 + 4 * g + r;
        int col = n0 + wc + ni * 16 + r16;
        float v = acc[mi][ni][r];
        if constexpr (EPI == 0) {
          int sec = col >> 10, cw = col & 1023;
          unsigned short hh, ll;
          split2(v, hh, ll);
          outP[(size_t)(2 * sec) * planeStride + (size_t)row * Cc + cw] = hh;
          outP[(size_t)(2 * sec + 1) * planeStride + (size_t)row * Cc + cw] = ll;
        } else {
          size_t o = (size_t)row * Nn + col;
          outF[o] = v + resid[o];
        }
      }
}

// ---------------- bf16 MFMA GEMM for FFN (global_load_lds staging) ----------------
template <int EPI>  // 2: +bias, GELU -> bf16 ; 3: +bias, +resid -> fp32
__global__ __launch_bounds__(256) void gemm_bt(const unsigned short* __restrict__ A,
                                               const unsigned short* __restrict__ W,
                                               float* __restrict__ outF,
                                               unsigned short* __restrict__ outB,
                                               const float* __restrict__ bias,
                                               const float* __restrict__ resid, int Nn, int Kk) {
  __shared__ __align__(16) unsigned short As[128 * 32];
  __shared__ __align__(16) unsigned short Bs[128 * 32];
  int m0 = blockIdx.x * 128, n0 = blockIdx.y * 128;
  int tid = threadIdx.x, lane = tid & 63, wid = tid >> 6;
  int wr = (wid >> 1) * 64, wc = (wid & 1) * 64;
  int g = lane >> 4, r16 = lane & 15;
  int srow[2], scc[2], sbase[2];
#pragma unroll
  for (int i = 0; i < 2; ++i) {
    int chunkbase = (wid * 2 + i) * 64;
    int chunk = chunkbase + lane;
    int row = chunk >> 2, sw = chunk & 3;
    srow[i] = row;
    scc[i] = (sw ^ (row & 3)) * 8;
    sbase[i] = chunkbase * 8;
  }
  f32x4 acc[4][4];
#pragma unroll
  for (int mi = 0; mi < 4; ++mi)
#pragma unroll
    for (int ni = 0; ni < 4; ++ni) acc[mi][ni] = (f32x4){0.f, 0.f, 0.f, 0.f};
  for (int k0 = 0; k0 < Kk; k0 += 32) {
    __syncthreads();
#pragma unroll
    for (int i = 0; i < 2; ++i) {
      gl16(&A[(size_t)(m0 + srow[i]) * Kk + k0 + scc[i]], &As[sbase[i]]);
      gl16(&W[(size_t)(n0 + srow[i]) * Kk + k0 + scc[i]], &Bs[sbase[i]]);
    }
    __syncthreads();
    short8 af[4], bfr[4];
#pragma unroll
    for (int mi = 0; mi < 4; ++mi) {
      int row = wr + mi * 16 + r16;
      af[mi] = *(short8*)&As[row * 32 + ((g ^ (row & 3)) * 8)];
    }
#pragma unroll
    for (int ni = 0; ni < 4; ++ni) {
      int row = wc + ni * 16 + r16;
      bfr[ni] = *(short8*)&Bs[row * 32 + ((g ^ (row & 3)) * 8)];
    }
    __builtin_amdgcn_s_setprio(1);
#pragma unroll
    for (int mi = 0; mi < 4; ++mi)
#pragma unroll
      for (int ni = 0; ni < 4; ++ni)
        acc[mi][ni] = __builtin_amdgcn_mfma_f32_16x16x32_bf16(af[mi], bfr[ni], acc[mi][ni], 0, 0, 0);
    __builtin_amdgcn_s_setprio(0);
  }
#pragma unroll
  for (int mi = 0; mi < 4; ++mi)
#pragma unroll
    for (int ni = 0; ni < 4; ++ni)
#pragma unroll
      for (int r = 0; r < 4; ++r) {
        int row = m0 + wr + mi * 16 + 4 * g + r;
        int col = n0 + wc + ni * 16 + r16;
        size_t o = (size_t)row * Nn + col;
        float v = acc[mi][ni][r];
        if constexpr (EPI == 2) {
          v += bias[col];
          v = 0.5f * v * (1.f + erff(v * 0.70710678118654752f));
          outB[o] = f2b(v);
        } else {
          v += bias[col];
          outF[o] = v + resid[o];
        }
      }
}

// ---------------- RoPE tables ----------------
__global__ __launch_bounds__(256) void rope_table(float* __restrict__ ct, float* __restrict__ st) {
  int idx = blockIdx.x * 256 + threadIdx.x;  // < T*64
  int t = idx >> 6, i = idx & 63;
  float e = (float)i * (1.f / 64.f);
  float p = powf(10000.0f, e);
  float inv = 1.0f / p;
  float ang = (float)t * inv;
  ct[idx] = cosf(ang);
  st[idx] = sinf(ang);
}

// ---------------- RoPE apply on q/k planes; K -> swizzled; qp/kp ----------------
__global__ __launch_bounds__(256) void rope_apply(unsigned short* __restrict__ qh_p,
                                                  unsigned short* __restrict__ ql_p,
                                                  const unsigned short* __restrict__ kh_p,
                                                  const unsigned short* __restrict__ kl_p,
                                                  unsigned short* __restrict__ khsw,
                                                  unsigned short* __restrict__ klsw,
                                                  const float* __restrict__ ct,
                                                  const float* __restrict__ st,
                                                  float* __restrict__ qp, float* __restrict__ kp) {
  int w = blockIdx.x * 4 + (threadIdx.x >> 6);  // (b,h,t)
  int lane = threadIdx.x & 63;
  int b = w / (Hh * Tt);
  int rem = w % (Hh * Tt);
  int h = rem / Tt;
  int t = rem % Tt;
  size_t base = (size_t)(b * Tt + t) * Cc + h * Dd;
  float cv = ct[t * 64 + lane], sv = st[t * 64 + lane];
  float q_lo = b2f(qh_p[base + lane]) + b2f(ql_p[base + lane]);
  float q_hi = b2f(qh_p[base + lane + 64]) + b2f(ql_p[base + lane + 64]);
  float qn_lo = q_lo * cv - q_hi * sv;
  float qn_hi = q_hi * cv + q_lo * sv;
  unsigned short hh, ll;
  split2(qn_lo, hh, ll);
  qh_p[base + lane] = hh; ql_p[base + lane] = ll;
  split2(qn_hi, hh, ll);
  qh_p[base + lane + 64] = hh; ql_p[base + lane + 64] = ll;
  float k_lo = b2f(kh_p[base + lane]) + b2f(kl_p[base + lane]);
  float k_hi = b2f(kh_p[base + lane + 64]) + b2f(kl_p[base + lane + 64]);
  float kn_lo = k_lo * cv - k_hi * sv;
  float kn_hi = k_hi * cv + k_lo * sv;
  size_t krow = ((size_t)(b * Hh + h) * Tt + t) * 128;
  int tsw = t & 7;
  int d0 = lane, d1 = lane + 64;
  int c0 = (((d0 >> 3) ^ tsw) << 3) | (d0 & 7);
  int c1 = (((d1 >> 3) ^ tsw) << 3) | (d1 & 7);
  split2(kn_lo, hh, ll);
  khsw[krow + c0] = hh; klsw[krow + c0] = ll;
  split2(kn_hi, hh, ll);
  khsw[krow + c1] = hh; klsw[krow + c1] = ll;
  float t0 = (((h >> 0) & 1) ? 1.f : -1.f) * 0.57735026918962576f;
  float t1 = (((h >> 1) & 1) ? 1.f : -1.f) * 0.57735026918962576f;
  float t2 = (((h >> 2) & 1) ? 1.f : -1.f) * 0.57735026918962576f;
  float q0v = __shfl(qn_lo, 0), q1v = __shfl(qn_lo, 1), q2v = __shfl(qn_lo, 2);
  float k0v = __shfl(kn_lo, 0), k1v = __shfl(kn_lo, 1), k2v = __shfl(kn_lo, 2);
  if (lane == 0) {
    qp[(size_t)(b * Hh + h) * Tt + t] = q0v * t0 + q1v * t1 + q2v * t2;
    kp[(size_t)(b * Hh + h) * Tt + t] = k0v * t0 + k1v * t1 + k2v * t2;
  }
}

// ---------------- V transpose: v planes -> vt[bh][d][t] ----------------
__global__ __launch_bounds__(256) void vtrans(const unsigned short* __restrict__ vh_p,
                                              const unsigned short* __restrict__ vl_p,
                                              unsigned short* __restrict__ vth,
                                              unsigned short* __restrict__ vtl) {
  __shared__ unsigned short Lh[64 * 68], Ll[64 * 68];
  int bidx = blockIdx.x;  // bh*64 + tt*2 + dd
  int dd = bidx & 1;
  int tt = (bidx >> 1) & 31;
  int bh = bidx >> 6;
  int b = bh >> 3, h = bh & 7;
  int tid = threadIdx.x;
#pragma unroll
  for (int it = 0; it < 2; ++it) {
    int chunk = tid + it * 256;  // 0..511
    int tr = chunk >> 3, c8 = chunk & 7;
    size_t src = (size_t)(b * Tt + tt * 64 + tr) * Cc + h * Dd + dd * 64 + c8 * 8;
    short8 vh = *(const short8*)&vh_p[src];
    short8 vl = *(const short8*)&vl_p[src];
    *(short4v*)&Lh[tr * 68 + c8 * 8] = *(short4v*)&vh;
    *(short4v*)&Lh[tr * 68 + c8 * 8 + 4] = *((short4v*)&vh + 1);
    *(short4v*)&Ll[tr * 68 + c8 * 8] = *(short4v*)&vl;
    *(short4v*)&Ll[tr * 68 + c8 * 8 + 4] = *((short4v*)&vl + 1);
  }
  __syncthreads();
#pragma unroll
  for (int it = 0; it < 2; ++it) {
    int chunk = tid + it * 256;
    int dr = chunk >> 3, t8 = chunk & 7;
    short8 oh, ol;
#pragma unroll
    for (int e = 0; e < 8; ++e) {
      oh[e] = (short)Lh[(t8 * 8 + e) * 68 + dr];
      ol[e] = (short)Ll[(t8 * 8 + e) * 68 + dr];
    }
    size_t dst = (size_t)(bh * Dd + dd * 64 + dr) * Tt + tt * 64 + t8 * 8;
    *(short8*)&vth[dst] = oh;
    *(short8*)&vtl[dst] = ol;
  }
}

// ---------------- fused causal flash attention v4 (T13 defer-rescale, tile split) ------
__global__ __launch_bounds__(256, 2) void attn_v3(
    const unsigned short* __restrict__ qh_p, const unsigned short* __restrict__ ql_p,
    const unsigned short* __restrict__ khsw, const unsigned short* __restrict__ klsw,
    const unsigned short* __restrict__ vth, const unsigned short* __restrict__ vtl,
    const float* __restrict__ qp, const float* __restrict__ kp,
    const float* __restrict__ head_scales, unsigned short* __restrict__ ao0,
    unsigned short* __restrict__ ao1, unsigned short* __restrict__ ao2) {
  int cix = blockIdx.x & 255, rix = blockIdx.x >> 8;
  int bh = cix >> 4, ii = cix & 15;
  int qblk = rix ? ii : 31 - ii;  // pairs (31-i, i): per-CU work uniform (68 tiles)
  int b = bh >> 3, h = bh & 7;
  int q0 = qblk * 64;
  int tid = threadIdx.x, lane = tid & 63, wid = tid >> 6;
  int wq0 = q0 + wid * 16;
  int g = lane >> 4, r16 = lane & 15;
  __shared__ __align__(16) unsigned short Ksh[32 * 128], Ksl[32 * 128];
  __shared__ __align__(16) unsigned short Vsh[128 * 34], Vsl[128 * 34];

  short8 qfh[4], qfl[4];
#pragma unroll
  for (int c4 = 0; c4 < 4; ++c4) {
    size_t qoff = (size_t)(b * Tt + wq0 + r16) * Cc + h * Dd + c4 * 32 + g * 8;
    qfh[c4] = *(const short8*)&qh_p[qoff];
    qfl[c4] = *(const short8*)&ql_p[qoff];
  }
  float hs = head_scales[h];
  const float* kpb = kp + (size_t)bh * Tt;
  float qpl2 = qp[(size_t)bh * Tt + wq0 + r16] * L2E;  // per-lane query proj (log2 dom)

  const unsigned short* Khb = khsw + (size_t)bh * Tt * 128;
  const unsigned short* Klb = klsw + (size_t)bh * Tt * 128;
  const unsigned short* Vhb = vth + (size_t)bh * Dd * Tt;
  const unsigned short* Vlb = vtl + (size_t)bh * Dd * Tt;

  f32x4 accA[8], accG[8];
#pragma unroll
  for (int n = 0; n < 8; ++n) {
    accA[n] = (f32x4){0.f, 0.f, 0.f, 0.f};
    accG[n] = (f32x4){0.f, 0.f, 0.f, 0.f};
  }
  float m1 = kNEG, l1 = 0.f, m2 = kNEG, l2 = 0.f;  // per-lane (query r16) stats
  const float scale2 = 0.08838834764831845f * L2E;

  int nt = 2 * qblk + 2;
  // stage registers (T14: issue next-tile loads before compute)
  short8 rkh[2], rkl[2], rvh[2], rvl[2];
  int krw[2], kcl[2], vdd[2], vkk[2];
#pragma unroll
  for (int it = 0; it < 2; ++it) {
    int chunk = tid + it * 256;
    krw[it] = chunk >> 4; kcl[it] = (chunk & 15) * 8;
    vdd[it] = chunk >> 2; vkk[it] = (chunk & 3) * 8;
  }
  auto LOADT = [&](int s0) {
#pragma unroll
    for (int it = 0; it < 2; ++it) {
      size_t ksrc = (size_t)(s0 + krw[it]) * 128 + kcl[it];
      rkh[it] = *(const short8*)&Khb[ksrc];
      rkl[it] = *(const short8*)&Klb[ksrc];
      size_t vsrc = (size_t)vdd[it] * Tt + s0 + vkk[it];
      rvh[it] = *(const short8*)&Vhb[vsrc];
      rvl[it] = *(const short8*)&Vlb[vsrc];
    }
  };
  LOADT(0);
  for (int t = 0; t < nt; ++t) {
    int s0 = t * 32;
    __syncthreads();  // previous tile fully read
#pragma unroll
    for (int it = 0; it < 2; ++it) {
      *(short8*)&Ksh[krw[it] * 128 + kcl[it]] = rkh[it];
      *(short8*)&Ksl[krw[it] * 128 + kcl[it]] = rkl[it];
      *(short8*)&Vsh[vdd[it] * 34 + vkk[it]] = rvh[it];
      *(short8*)&Vsl[vdd[it] * 34 + vkk[it]] = rvl[it];
    }
    __syncthreads();  // tile ready
    if (t + 1 < nt) LOADT(s0 + 32);  // overlap next loads with compute
    if (s0 > wq0 + 15) continue;
    float kpv[2][4];
#pragma unroll
    for (int st2 = 0; st2 < 2; ++st2)
#pragma unroll
      for (int rr = 0; rr < 4; ++rr) kpv[st2][rr] = kpb[s0 + st2 * 16 + 4 * g + rr];
    // S^T = K·Q^T: lane (g,r16) holds S[query r16][key s0+st2*16+4g+rr]
    f32x4 sf[2];
    sf[0] = (f32x4){0.f, 0.f, 0.f, 0.f};
    sf[1] = (f32x4){0.f, 0.f, 0.f, 0.f};
    __builtin_amdgcn_s_setprio(1);
#pragma unroll
    for (int st2 = 0; st2 < 2; ++st2) {
      int row = st2 * 16 + r16, rsw = row & 7;
#pragma unroll
      for (int c4 = 0; c4 < 4; ++c4) {
        int off = row * 128 + (((c4 * 4 + g) ^ rsw) * 8);
        short8 kh8 = *(short8*)&Ksh[off];
        short8 kl8 = *(short8*)&Ksl[off];
        sf[st2] = __builtin_amdgcn_mfma_f32_16x16x32_bf16(kl8, qfh[c4], sf[st2], 0, 0, 0);
        sf[st2] = __builtin_amdgcn_mfma_f32_16x16x32_bf16(kh8, qfl[c4], sf[st2], 0, 0, 0);
        sf[st2] = __builtin_amdgcn_mfma_f32_16x16x32_bf16(kh8, qfh[c4], sf[st2], 0, 0, 0);
      }
    }
    __builtin_amdgcn_s_setprio(0);
    // scores (log2 domain); mask VALU only on diagonal tiles
    bool partial = (s0 + 31) > wq0;
    float sv[2][4], gvv[2][4];
    float mx = kNEG, gmx = kNEG;
#pragma unroll
    for (int st2 = 0; st2 < 2; ++st2)
#pragma unroll
      for (int rr = 0; rr < 4; ++rr) {
        float s = sf[st2][rr] * scale2;
        float gg = qpl2 * kpv[st2][rr];
        if (partial) {
          int key = s0 + st2 * 16 + 4 * g + rr;
          bool ok = key <= wq0 + r16;
          s = ok ? s : kNEG;
          gg = ok ? gg : kNEG;
        }
        sv[st2][rr] = s; gvv[st2][rr] = gg;
        mx = fmaxf(mx, s);
        gmx = fmaxf(gmx, gg);
      }
    mx = fmaxf(mx, __shfl_xor(mx, 16));
    mx = fmaxf(mx, __shfl_xor(mx, 32));
    gmx = fmaxf(gmx, __shfl_xor(gmx, 16));
    gmx = fmaxf(gmx, __shfl_xor(gmx, 32));
    // T13 defer-rescale (log2 dom, THR=7 -> P <= 128)
    if (!__all(mx <= m1 + 7.f)) {
      float nm = fmaxf(m1, mx);
      float sc = exp2f(m1 - nm);
      m1 = nm; l1 *= sc;
      float sA[4];
#pragma unroll
      for (int rr = 0; rr < 4; ++rr) sA[rr] = __shfl(sc, 4 * g + rr);
#pragma unroll
      for (int n = 0; n < 8; ++n)
#pragma unroll
        for (int rr = 0; rr < 4; ++rr) accA[n][rr] *= sA[rr];
    }
    if (!__all(gmx <= m2 + 7.f)) {
      float nm = fmaxf(m2, gmx);
      float sg = exp2f(m2 - nm);
      m2 = nm; l2 *= sg;
      float sG[4];
#pragma unroll
      for (int rr = 0; rr < 4; ++rr) sG[rr] = __shfl(sg, 4 * g + rr);
#pragma unroll
      for (int n = 0; n < 8; ++n)
#pragma unroll
        for (int rr = 0; rr < 4; ++rr) accG[n][rr] *= sG[rr];
    }
    float pa[2][4], pgv[2][4];
    float ps = 0.f, pgs = 0.f;
#pragma unroll
    for (int st2 = 0; st2 < 2; ++st2)
#pragma unroll
      for (int rr = 0; rr < 4; ++rr) {
        float p = exp2f(sv[st2][rr] - m1);  // masked: exp2(-huge)=0
        pa[st2][rr] = p; ps += p;
        float pq = exp2f(gvv[st2][rr] - m2);
        pgv[st2][rr] = pq; pgs += pq;
      }
    ps += __shfl_xor(ps, 16); ps += __shfl_xor(ps, 32);
    pgs += __shfl_xor(pgs, 16); pgs += __shfl_xor(pgs, 32);
    l1 += ps;
    l2 += pgs;
    // pack P directly as A-fragment via key permutation κ(g,e)=(e>>2)*16+4g+(e&3)
    short8 pAh, pAl, pGh, pGl;
#pragma unroll
    for (int e = 0; e < 8; ++e) {
      unsigned short hh, ll;
      split2(pa[e >> 2][e & 3], hh, ll);
      pAh[e] = (short)hh; pAl[e] = (short)ll;
      split2(pgv[e >> 2][e & 3], hh, ll);
      pGh[e] = (short)hh; pGl[e] = (short)ll;
    }
    // PV: B-fragment = V[κ(g,e)][d] (two 4-key runs per lane)
    __builtin_amdgcn_s_setprio(1);
#pragma unroll
    for (int n = 0; n < 8; ++n) {
      int dofs = (n * 16 + r16) * 34;
      short8 vh8, vl8;
      *(short4v*)&vh8 = *(short4v*)&Vsh[dofs + 4 * g];
      *((short4v*)&vh8 + 1) = *(short4v*)&Vsh[dofs + 16 + 4 * g];
      *(short4v*)&vl8 = *(short4v*)&Vsl[dofs + 4 * g];
      *((short4v*)&vl8 + 1) = *(short4v*)&Vsl[dofs + 16 + 4 * g];
      accA[n] = __builtin_amdgcn_mfma_f32_16x16x32_bf16(pAl, vh8, accA[n], 0, 0, 0);
      accA[n] = __builtin_amdgcn_mfma_f32_16x16x32_bf16(pAh, vl8, accA[n], 0, 0, 0);
      accA[n] = __builtin_amdgcn_mfma_f32_16x16x32_bf16(pAh, vh8, accA[n], 0, 0, 0);
      accG[n] = __builtin_amdgcn_mfma_f32_16x16x32_bf16(pGl, vh8, accG[n], 0, 0, 0);
      accG[n] = __builtin_amdgcn_mfma_f32_16x16x32_bf16(pGh, vl8, accG[n], 0, 0, 0);
      accG[n] = __builtin_amdgcn_mfma_f32_16x16x32_bf16(pGh, vh8, accG[n], 0, 0, 0);
    }
    __builtin_amdgcn_s_setprio(0);
  }
  // epilogue: fetch l for query 4g+rr, combine, split3 to planes
  float lA[4], lG[4];
#pragma unroll
  for (int rr = 0; rr < 4; ++rr) {
    lA[rr] = __shfl(l1, 4 * g + rr);
    lG[rr] = __shfl(l2, 4 * g + rr);
  }
#pragma unroll
  for (int n = 0; n < 8; ++n)
#pragma unroll
    for (int rr = 0; rr < 4; ++rr) {
      int qi = wq0 + 4 * g + rr;
      float av = accA[n][rr] / lA[rr];
      float gq = accG[n][rr] / lG[rr];
      float o = av + hs * (gq - av);
      unsigned short s1, s2v, s3;
      split3(o, s1, s2v, s3);
      size_t oo = (size_t)(b * Tt + qi) * Cc + h * Dd + n * 16 + r16;
      ao0[oo] = s1; ao1[oo] = s2v; ao2[oo] = s3;
    }
}

// ---------------- hexagram VQ + FFN-LN prep ----------------
__global__ __launch_bounds__(256) void hex_kernel(float* __restrict__ x1,
                                                  const float* __restrict__ hg,
                                                  const float* __restrict__ hb,
                                                  const float* __restrict__ to_qd,
                                                  const float* __restrict__ from_qd,
                                                  const float* __restrict__ hex_scale,
                                                  const float* __restrict__ fg,
                                                  const float* __restrict__ fb,
                                                  unsigned short* __restrict__ h_ffn) {
  int row = blockIdx.x * 4 + (threadIdx.x >> 6);
  int lane = threadIdx.x & 63;
  float* xr = x1 + (size_t)row * Cc;
  float v[16];
  float s = 0.f;
#pragma unroll
  for (int c = 0; c < 4; ++c) {
    float4 t = *(const float4*)&xr[c * 256 + lane * 4];
    v[c * 4 + 0] = t.x; v[c * 4 + 1] = t.y; v[c * 4 + 2] = t.z; v[c * 4 + 3] = t.w;
    s += t.x + t.y + t.z + t.w;
  }
  s = wave_sum(s);
  float mean = s * (1.f / Cc);
  float s2 = 0.f;
#pragma unroll
  for (int j = 0; j < 16; ++j) { float d = v[j] - mean; s2 += d * d; }
  s2 = wave_sum(s2);
  float rstd = 1.0f / sqrtf(s2 * (1.f / Cc) + 1e-5f);
  float zq[6] = {0.f, 0.f, 0.f, 0.f, 0.f, 0.f};
#pragma unroll
  for (int c = 0; c < 4; ++c)
#pragma unroll
    for (int j2 = 0; j2 < 4; ++j2) {
      int idx = c * 256 + lane * 4 + j2;
      float hv = (v[c * 4 + j2] - mean) * rstd * hg[idx] + hb[idx];
#pragma unroll
      for (int j = 0; j < 6; ++j) zq[j] += hv * to_qd[j * Cc + idx];
    }
#pragma unroll
  for (int j = 0; j < 6; ++j) zq[j] = wave_sum(zq[j]);
  float hsc = hex_scale[0];
  float hard[6];
#pragma unroll
  for (int j = 0; j < 6; ++j) hard[j] = (zq[j] >= 0.f) ? hsc : -hsc;
  float x2v[16];
  float t1 = 0.f;
#pragma unroll
  for (int c = 0; c < 4; ++c)
#pragma unroll
    for (int j2 = 0; j2 < 4; ++j2) {
      int idx = c * 256 + lane * 4 + j2;
      float a = 0.f;
#pragma unroll
      for (int j = 0; j < 6; ++j) a += hard[j] * from_qd[idx * 6 + j];
      float xv = v[c * 4 + j2] + a;
      x2v[c * 4 + j2] = xv;
      t1 += xv;
    }
  t1 = wave_sum(t1);
  float mean2 = t1 * (1.f / Cc);
  float t2 = 0.f;
#pragma unroll
  for (int j = 0; j < 16; ++j) { float d = x2v[j] - mean2; t2 += d * d; }
  t2 = wave_sum(t2);
  float rstd2 = 1.0f / sqrtf(t2 * (1.f / Cc) + 1e-5f);
#pragma unroll
  for (int c = 0; c < 4; ++c) {
    float4 t;
    t.x = x2v[c * 4 + 0]; t.y = x2v[c * 4 + 1]; t.z = x2v[c * 4 + 2]; t.w = x2v[c * 4 + 3];
    *(float4*)&xr[c * 256 + lane * 4] = t;
    short4v o;
#pragma unroll
    for (int j = 0; j < 4; ++j) {
      int idx = c * 256 + lane * 4 + j;
      ((short*)&o)[j] = (short)f2b((x2v[c * 4 + j] - mean2) * rstd2 * fg[idx] + fb[idx]);
    }
    *(short4v*)&h_ffn[(size_t)row * Cc + c * 256 + lane * 4] = o;
  }
}

}  // namespace

extern "C" void kernel_launch(void* const* d_in, const int* in_sizes, int n_in, void* d_out,
                              int out_size, void* d_ws, size_t ws_size, hipStream_t stream) {
  const float* x = (const float*)d_in[0];
  const float* ln_attn_g = (const float*)d_in[1];
  const float* ln_attn_b = (const float*)d_in[2];
  const float* qkv_w = (const float*)d_in[3];
  const float* out_w = (const float*)d_in[4];
  const float* head_scales = (const float*)d_in[5];
  const float* ln_hex_g = (const float*)d_in[6];
  const float* ln_hex_b = (const float*)d_in[7];
  const float* to_qd_w = (const float*)d_in[8];
  const float* from_qd_w = (const float*)d_in[9];
  const float* hex_scale = (const float*)d_in[10];
  const float* ln_ffn_g = (const float*)d_in[11];
  const float* ln_ffn_b = (const float*)d_in[12];
  const float* ffn_w1 = (const float*)d_in[13];
  const float* ffn_b1 = (const float*)d_in[14];
  const float* ffn_w2 = (const float*)d_in[15];
  const float* ffn_b2 = (const float*)d_in[16];

  unsigned short* ws16 = (unsigned short*)d_ws;
  const size_t PL = (size_t)Mrows * Cc;  // 4,194,304 elems = 8 MB per plane
  unsigned short* hh = ws16 + 0 * PL;    // LN hi   -> later ao0
  unsigned short* hl = ws16 + 1 * PL;    // LN lo   -> later ao1
  unsigned short* qhp = ws16 + 2 * PL;   // Q hi    -> later w1b
  unsigned short* qlp = ws16 + 3 * PL;   // Q lo    -> later w2b
  unsigned short* khp = ws16 + 4 * PL;   // K hi    -> later ao2
  unsigned short* klp = ws16 + 5 * PL;   // K lo    -> later x1 (with vhp)
  unsigned short* vhp = ws16 + 6 * PL;   // V hi
  unsigned short* vlp = ws16 + 7 * PL;   // V lo    -> later h_ffn
  unsigned short* khsw = ws16 + 8 * PL;  // -> later ow planes / gelu (4 planes)
  unsigned short* klsw = ws16 + 9 * PL;
  unsigned short* vth = ws16 + 10 * PL;  // first: wqh
  unsigned short* vtl = ws16 + 11 * PL;  // first: wql
  float* tail = (float*)(ws16 + 12 * PL);
  float* ct = tail;
  float* st = ct + (size_t)Tt * 64;
  float* qp = st + (size_t)Tt * 64;
  float* kp = qp + (size_t)Bb * Hh * Tt;
  // aliases
  unsigned short* ao0 = hh;
  unsigned short* ao1 = hl;
  unsigned short* ao2 = khp;
  float* x1 = (float*)klp;  // spans klp+vhp (16.78 MB fp32)
  unsigned short* h_ffn = vlp;
  unsigned short* w1b = qhp;
  unsigned short* w2b = qlp;
  unsigned short* gelu = khsw;  // spans khsw..vtl (33.55 MB)
  unsigned short* wqh = vth;
  unsigned short* wql = vtl;
  unsigned short* ow0 = khsw;
  unsigned short* ow1 = khsw + (size_t)Cc * Cc;
  unsigned short* ow2 = khsw + (size_t)2 * Cc * Cc;

  // 1) LN(attn) -> split2 planes
  ln_split<<<Mrows / 4, 256, 0, stream>>>(x, ln_attn_g, ln_attn_b, hh, hl);
  // 2) qkv_w pre-split
  wsplit2_k<<<(3 * Cc * Cc) / 1024, 256, 0, stream>>>(qkv_w, wqh, wql, 3 * Cc * Cc);
  // 3) QKV GEMM (3-pass) -> q/k/v split2 planes
  gemm_pn<2, 0><<<dim3(Mrows / 128, (3 * Cc) / 128), 256, 0, stream>>>(
      hh, hl, nullptr, wqh, wql, nullptr, qhp, PL, nullptr, nullptr, 3 * Cc, Cc);
  // 4) RoPE + K-swizzle + trigram projections
  rope_table<<<(Tt * 64) / 256, 256, 0, stream>>>(ct, st);
  rope_apply<<<(Bb * Hh * Tt) / 4, 256, 0, stream>>>(qhp, qlp, khp, klp, khsw, klsw, ct, st, qp,
                                                     kp);
  // 5) V transpose (overwrites wqh/wql — dead)
  vtrans<<<Bb * Hh * 32 * 2, 256, 0, stream>>>(vhp, vlp, vth, vtl);
  // 6) fused attention -> split3 attn planes
  attn_v3<<<512, 256, 0, stream>>>(qhp, qlp, khsw, klsw, vth, vtl, qp, kp, head_scales, ao0, ao1,
                                   ao2);
  // 7) out_w pre-split (khsw dead)
  wsplit3_k<<<(Cc * Cc) / 1024, 256, 0, stream>>>(out_w, ow0, ow1, ow2, Cc * Cc);
  // 8) out-proj (6-pass) + residual -> x1
  gemm_pn<3, 1><<<dim3(Mrows / 128, Cc / 128), 256, 0, stream>>>(
      ao0, ao1, ao2, ow0, ow1, ow2, nullptr, 0, x1, x, Cc, Cc);
  // 9) hexagram VQ + FFN LN prep
  hex_kernel<<<Mrows / 4, 256, 0, stream>>>(x1, ln_hex_g, ln_hex_b, to_qd_w, from_qd_w, hex_scale,
                                            ln_ffn_g, ln_ffn_b, h_ffn);
  // 10) FFN weight casts (q planes dead)
  cast_kernel<<<(FFNd * Cc) / 1024, 256, 0, stream>>>(ffn_w1, w1b, FFNd * Cc);
  cast_kernel<<<(Cc * FFNd) / 1024, 256, 0, stream>>>(ffn_w2, w2b, Cc * FFNd);
  // 11) FFN
  gemm_bt<2><<<dim3(Mrows / 128, FFNd / 128), 256, 0, stream>>>(h_ffn, w1b, nullptr, gelu, ffn_b1,
                                                                nullptr, FFNd, Cc);
  gemm_bt<3><<<dim3(Mrows / 128, Cc / 128), 256, 0, stream>>>(gelu, w2b, (float*)d_out, nullptr,
                                                              ffn_b2, x1, Cc, FFNd);
}